// Round 1
// baseline (865.858 us; speedup 1.0000x reference)
//
#include <hip/hip_runtime.h>
#include <cstdint>
#include <cstddef>

#define H 256
#define EMB 16
#define ED 5
#define BN_EPS 1e-5f

// -------------------------------------------------------------------------
// GEMM (input layer): h0 = relu(concat(x, gemb[gid]) @ W_in + b_in)
// A is materialized on the fly from x [N,F] and gemb[gid] [N,EMB]. K = F+EMB.
// Tile 64x64, 256 threads, 4x4 micro-tile. N rows and 256 cols divide by 64.
// -------------------------------------------------------------------------
__global__ __launch_bounds__(256) void gemm_in_kernel(
    const float* __restrict__ x, const int* __restrict__ gid,
    const float* __restrict__ gemb, const float* __restrict__ W,
    const float* __restrict__ bias, float* __restrict__ C, int F, int N) {
  const int tx = threadIdx.x & 15;
  const int ty = threadIdx.x >> 4;
  const int m0 = blockIdx.y * 64;
  const int n0 = blockIdx.x * 64;
  __shared__ float As[16][68];   // +4 pad: conflict-free, keeps 16B alignment
  __shared__ float Bs[16][68];
  float acc[4][4] = {};
  const int lm  = threadIdx.x >> 2;        // 0..63: A-stage row
  const int lk4 = (threadIdx.x & 3) * 4;   // A-stage k offset
  const int lkb = threadIdx.x >> 4;        // 0..15: B-stage k
  const int lnb = (threadIdx.x & 15) * 4;  // B-stage col*4
  const int g   = gid[m0 + lm];
  const int KTOT = F + EMB;  // 132
  for (int k0 = 0; k0 < KTOT; k0 += 16) {
    __syncthreads();
    #pragma unroll
    for (int i = 0; i < 4; ++i) {
      int k = k0 + lk4 + i;
      float v = 0.f;
      if (k < F) v = x[(size_t)(m0 + lm) * F + k];
      else if (k < KTOT) v = gemb[g * EMB + (k - F)];
      As[lk4 + i][lm] = v;
    }
    {
      int k = k0 + lkb;
      float4 bv = make_float4(0.f, 0.f, 0.f, 0.f);
      if (k < KTOT) bv = *(const float4*)(W + (size_t)k * H + n0 + lnb);
      *(float4*)&Bs[lkb][lnb] = bv;
    }
    __syncthreads();
    #pragma unroll
    for (int k = 0; k < 16; ++k) {
      const float4 a4 = *(const float4*)&As[k][ty * 4];
      const float4 b4 = *(const float4*)&Bs[k][tx * 4];
      const float ar[4] = {a4.x, a4.y, a4.z, a4.w};
      const float br[4] = {b4.x, b4.y, b4.z, b4.w};
      #pragma unroll
      for (int i = 0; i < 4; ++i)
        #pragma unroll
        for (int j = 0; j < 4; ++j)
          acc[i][j] = fmaf(ar[i], br[j], acc[i][j]);
    }
  }
  const float4 bias4 = *(const float4*)(bias + n0 + tx * 4);
  const float bb[4] = {bias4.x, bias4.y, bias4.z, bias4.w};
  #pragma unroll
  for (int i = 0; i < 4; ++i) {
    int row = m0 + ty * 4 + i;
    float4 o;
    o.x = fmaxf(acc[i][0] + bb[0], 0.f);
    o.y = fmaxf(acc[i][1] + bb[1], 0.f);
    o.z = fmaxf(acc[i][2] + bb[2], 0.f);
    o.w = fmaxf(acc[i][3] + bb[3], 0.f);
    *(float4*)(C + (size_t)row * H + n0 + tx * 4) = o;
  }
}

// -------------------------------------------------------------------------
// GEMM (MLP layers, K=256): C = relu(A @ B + bias), same tiling.
// -------------------------------------------------------------------------
__global__ __launch_bounds__(256) void gemm256_kernel(
    const float* __restrict__ A, const float* __restrict__ B,
    const float* __restrict__ bias, float* __restrict__ C, int N) {
  const int tx = threadIdx.x & 15;
  const int ty = threadIdx.x >> 4;
  const int m0 = blockIdx.y * 64;
  const int n0 = blockIdx.x * 64;
  __shared__ float As[16][68];
  __shared__ float Bs[16][68];
  float acc[4][4] = {};
  const int lm  = threadIdx.x >> 2;
  const int lk4 = (threadIdx.x & 3) * 4;
  const int lkb = threadIdx.x >> 4;
  const int lnb = (threadIdx.x & 15) * 4;
  for (int k0 = 0; k0 < 256; k0 += 16) {
    __syncthreads();
    {
      const float4 av = *(const float4*)(A + (size_t)(m0 + lm) * 256 + k0 + lk4);
      As[lk4 + 0][lm] = av.x;
      As[lk4 + 1][lm] = av.y;
      As[lk4 + 2][lm] = av.z;
      As[lk4 + 3][lm] = av.w;
    }
    {
      const float4 bv = *(const float4*)(B + (size_t)(k0 + lkb) * H + n0 + lnb);
      *(float4*)&Bs[lkb][lnb] = bv;
    }
    __syncthreads();
    #pragma unroll
    for (int k = 0; k < 16; ++k) {
      const float4 a4 = *(const float4*)&As[k][ty * 4];
      const float4 b4 = *(const float4*)&Bs[k][tx * 4];
      const float ar[4] = {a4.x, a4.y, a4.z, a4.w};
      const float br[4] = {b4.x, b4.y, b4.z, b4.w};
      #pragma unroll
      for (int i = 0; i < 4; ++i)
        #pragma unroll
        for (int j = 0; j < 4; ++j)
          acc[i][j] = fmaf(ar[i], br[j], acc[i][j]);
    }
  }
  const float4 bias4 = *(const float4*)(bias + n0 + tx * 4);
  const float bb[4] = {bias4.x, bias4.y, bias4.z, bias4.w};
  #pragma unroll
  for (int i = 0; i < 4; ++i) {
    int row = m0 + ty * 4 + i;
    float4 o;
    o.x = fmaxf(acc[i][0] + bb[0], 0.f);
    o.y = fmaxf(acc[i][1] + bb[1], 0.f);
    o.z = fmaxf(acc[i][2] + bb[2], 0.f);
    o.w = fmaxf(acc[i][3] + bb[3], 0.f);
    *(float4*)(C + (size_t)row * H + n0 + tx * 4) = o;
  }
}

// -------------------------------------------------------------------------
// BatchNorm stats: per-column sum and sum-of-squares of h0 (post-relu).
// 256 blocks x 256 threads; thread j handles column j over N/256 rows.
// -------------------------------------------------------------------------
__global__ __launch_bounds__(256) void bn_stats_kernel(
    const float* __restrict__ h0, float* __restrict__ stats, int N) {
  const int j = threadIdx.x;
  const int rpb = N >> 8;  // rows per block (N divisible by 256)
  const int r0 = blockIdx.x * rpb;
  float s = 0.f, ss = 0.f;
  for (int r = 0; r < rpb; ++r) {
    float v = h0[(size_t)(r0 + r) * H + j];
    s += v;
    ss = fmaf(v, v, ss);
  }
  atomicAdd(&stats[j], s);
  atomicAdd(&stats[H + j], ss);
}

// stats[512+j] = a_j = gamma*rsigma ; stats[768+j] = b_j = beta - mu*a
__global__ void bn_finalize_kernel(const float* __restrict__ gamma,
                                   const float* __restrict__ beta,
                                   float* __restrict__ stats, int N) {
  const int j = threadIdx.x;
  const float inv_n = 1.0f / (float)N;
  const float mu = stats[j] * inv_n;
  const float var = stats[H + j] * inv_n - mu * mu;
  const float rs = 1.0f / sqrtf(var + BN_EPS);
  const float a = gamma[j] * rs;
  stats[2 * H + j] = a;
  stats[3 * H + j] = beta[j] - mu * a;
}

// -------------------------------------------------------------------------
// CSR build: degree histogram -> exclusive scan -> scatter edge ids.
// -------------------------------------------------------------------------
__global__ __launch_bounds__(256) void csr_count_kernel(
    const int* __restrict__ ei, int* __restrict__ deg, int E) {
  int e = blockIdx.x * 256 + threadIdx.x;
  if (e < E) atomicAdd(&deg[ei[E + e]], 1);  // row 1 = dst
}

__global__ __launch_bounds__(1024) void scan_kernel(
    const int* __restrict__ deg, int* __restrict__ row_start,
    int* __restrict__ cursor, int n) {
  __shared__ int warp_sums[16];
  __shared__ int s_carry;
  const int lane = threadIdx.x & 63;
  const int wid = threadIdx.x >> 6;
  if (threadIdx.x == 0) s_carry = 0;
  __syncthreads();
  for (int base = 0; base < n; base += 1024) {
    int i = base + threadIdx.x;
    int v = (i < n) ? deg[i] : 0;
    int xi = v;
    #pragma unroll
    for (int d = 1; d < 64; d <<= 1) {
      int y = __shfl_up(xi, d, 64);
      if (lane >= d) xi += y;
    }
    if (lane == 63) warp_sums[wid] = xi;
    __syncthreads();
    if (wid == 0 && lane < 16) {
      int ws = warp_sums[lane];
      #pragma unroll
      for (int d = 1; d < 16; d <<= 1) {
        int y = __shfl_up(ws, d, 16);
        if (lane >= d) ws += y;
      }
      warp_sums[lane] = ws;  // inclusive
    }
    __syncthreads();
    int wave_off = (wid == 0) ? 0 : warp_sums[wid - 1];
    int excl = s_carry + wave_off + (xi - v);
    int total = warp_sums[15];
    if (i < n) {
      row_start[i] = excl;
      cursor[i] = excl;
    }
    __syncthreads();
    if (threadIdx.x == 0) s_carry += total;
    __syncthreads();
  }
  if (threadIdx.x == 0) row_start[n] = s_carry;
}

__global__ __launch_bounds__(256) void csr_scatter_kernel(
    const int* __restrict__ ei, int* __restrict__ cursor,
    int* __restrict__ csr_eid, int E) {
  int e = blockIdx.x * 256 + threadIdx.x;
  if (e < E) {
    int d = ei[E + e];
    int p = atomicAdd(&cursor[d], 1);
    csr_eid[p] = e;
  }
}

// -------------------------------------------------------------------------
// GINE aggregation, one wave per destination node. BN applied lazily as
// per-column affine a*h0+b (a,b in stats[512..]). Each lane owns 4 columns.
//   msg = relu(a*h0[src]+b + edge_attr @ We + be); z = a*h0[n]+b + sum(msg)
// -------------------------------------------------------------------------
__global__ __launch_bounds__(256) void aggregate_kernel(
    const float* __restrict__ h0, const int* __restrict__ ei,
    const float* __restrict__ ea, const float* __restrict__ We,
    const float* __restrict__ be, const float* __restrict__ stats,
    const int* __restrict__ row_start, const int* __restrict__ csr_eid,
    float* __restrict__ z, int N, int E) {
  const int lane = threadIdx.x & 63;
  const int n = blockIdx.x * 4 + (threadIdx.x >> 6);
  if (n >= N) return;
  const int c = lane * 4;
  const float4 a4  = *(const float4*)(stats + 2 * H + c);
  const float4 b4  = *(const float4*)(stats + 3 * H + c);
  const float4 be4 = *(const float4*)(be + c);
  const float4 w0 = *(const float4*)(We + 0 * H + c);
  const float4 w1 = *(const float4*)(We + 1 * H + c);
  const float4 w2 = *(const float4*)(We + 2 * H + c);
  const float4 w3 = *(const float4*)(We + 3 * H + c);
  const float4 w4 = *(const float4*)(We + 4 * H + c);
  float4 agg = make_float4(0.f, 0.f, 0.f, 0.f);
  const int s0 = row_start[n], s1 = row_start[n + 1];
  for (int i = s0; i < s1; ++i) {
    const int e = csr_eid[i];
    const int src = ei[e];  // row 0 = src
    const float* eap = ea + (size_t)e * ED;
    const float e0 = eap[0], e1 = eap[1], e2 = eap[2], e3 = eap[3], e4 = eap[4];
    const float4 h4 = *(const float4*)(h0 + (size_t)src * H + c);
    float mx = fmaf(a4.x, h4.x, b4.x) + be4.x;
    float my = fmaf(a4.y, h4.y, b4.y) + be4.y;
    float mz = fmaf(a4.z, h4.z, b4.z) + be4.z;
    float mw = fmaf(a4.w, h4.w, b4.w) + be4.w;
    mx = fmaf(e0, w0.x, mx); my = fmaf(e0, w0.y, my); mz = fmaf(e0, w0.z, mz); mw = fmaf(e0, w0.w, mw);
    mx = fmaf(e1, w1.x, mx); my = fmaf(e1, w1.y, my); mz = fmaf(e1, w1.z, mz); mw = fmaf(e1, w1.w, mw);
    mx = fmaf(e2, w2.x, mx); my = fmaf(e2, w2.y, my); mz = fmaf(e2, w2.z, mz); mw = fmaf(e2, w2.w, mw);
    mx = fmaf(e3, w3.x, mx); my = fmaf(e3, w3.y, my); mz = fmaf(e3, w3.z, mz); mw = fmaf(e3, w3.w, mw);
    mx = fmaf(e4, w4.x, mx); my = fmaf(e4, w4.y, my); mz = fmaf(e4, w4.z, mz); mw = fmaf(e4, w4.w, mw);
    agg.x += fmaxf(mx, 0.f);
    agg.y += fmaxf(my, 0.f);
    agg.z += fmaxf(mz, 0.f);
    agg.w += fmaxf(mw, 0.f);
  }
  const float4 hh = *(const float4*)(h0 + (size_t)n * H + c);
  float4 zz;
  zz.x = fmaf(a4.x, hh.x, b4.x) + agg.x;
  zz.y = fmaf(a4.y, hh.y, b4.y) + agg.y;
  zz.z = fmaf(a4.z, hh.z, b4.z) + agg.z;
  zz.w = fmaf(a4.w, hh.w, b4.w) + agg.w;
  *(float4*)(z + (size_t)n * H + c) = zz;
}

// -------------------------------------------------------------------------
extern "C" void kernel_launch(void* const* d_in, const int* in_sizes, int n_in,
                              void* d_out, int out_size, void* d_ws, size_t ws_size,
                              hipStream_t stream) {
  const float* x     = (const float*)d_in[0];
  const int*   ei    = (const int*)d_in[1];   // [2,E]: row0=src, row1=dst
  const float* ea    = (const float*)d_in[2];
  const int*   gid   = (const int*)d_in[3];
  const float* gemb  = (const float*)d_in[4];
  const float* W_in  = (const float*)d_in[5];
  const float* b_in  = (const float*)d_in[6];
  const float* gamma = (const float*)d_in[7];
  const float* beta  = (const float*)d_in[8];
  const float* We    = (const float*)d_in[9];
  const float* be    = (const float*)d_in[10];
  const float* W1    = (const float*)d_in[11];
  const float* b1    = (const float*)d_in[12];
  const float* W2    = (const float*)d_in[13];
  const float* b2    = (const float*)d_in[14];
  float* out = (float*)d_out;

  const int N = in_sizes[3];           // 59392 (divisible by 256)
  const int E = in_sizes[1] / 2;       // 950272 (divisible by 256)
  const int F = in_sizes[0] / N;       // 116

  // workspace layout
  float* stats = (float*)d_ws;               // 1024 floats: sum, sumsq, a, b
  int* deg = (int*)(stats + 1024);           // N
  int* row_start = deg + N;                  // N+1
  int* cursor = row_start + N + 1;           // N
  int* csr_eid = cursor + N;                 // E
  uintptr_t pa = (uintptr_t)(csr_eid + E);
  pa = (pa + 255) & ~(uintptr_t)255;
  float* h0 = (float*)pa;                    // N*H
  float* z  = h0 + (size_t)N * H;            // N*H
  float* hidden = h0;                        // reuse: h0 dead after z written

  // zero BN accumulators + degree histogram (contiguous)
  hipMemsetAsync(d_ws, 0, (size_t)(1024 + N) * sizeof(int), stream);

  dim3 gemm_grid(H / 64, N / 64);
  gemm_in_kernel<<<gemm_grid, 256, 0, stream>>>(x, gid, gemb, W_in, b_in, h0, F, N);
  bn_stats_kernel<<<256, 256, 0, stream>>>(h0, stats, N);
  bn_finalize_kernel<<<1, 256, 0, stream>>>(gamma, beta, stats, N);

  csr_count_kernel<<<(E + 255) / 256, 256, 0, stream>>>(ei, deg, E);
  scan_kernel<<<1, 1024, 0, stream>>>(deg, row_start, cursor, N);
  csr_scatter_kernel<<<(E + 255) / 256, 256, 0, stream>>>(ei, cursor, csr_eid, E);

  aggregate_kernel<<<(N + 3) / 4, 256, 0, stream>>>(h0, ei, ea, We, be, stats,
                                                    row_start, csr_eid, z, N, E);

  gemm256_kernel<<<gemm_grid, 256, 0, stream>>>(z, W1, b1, hidden, N);
  gemm256_kernel<<<gemm_grid, 256, 0, stream>>>(hidden, W2, b2, out, N);

  // passthrough second output: edge_attr
  hipMemcpyAsync(out + (size_t)N * H, ea, (size_t)E * ED * sizeof(float),
                 hipMemcpyDeviceToDevice, stream);
}

// Round 2
// 662.176 us; speedup vs baseline: 1.3076x; 1.3076x over previous
//
#include <hip/hip_runtime.h>
#include <hip/hip_bf16.h>
#include <cstdint>
#include <cstddef>

#define H 256
#define EMB 16
#define ED 5
#define BN_EPS 1e-5f

typedef __attribute__((ext_vector_type(8))) short short8;
typedef __attribute__((ext_vector_type(4))) float f32x4;

__device__ __forceinline__ unsigned short f2bf(float f) {
  unsigned int u = __float_as_uint(f);
  unsigned int r = (u + 0x7fffu + ((u >> 16) & 1u)) >> 16;
  return (unsigned short)r;
}
__device__ __forceinline__ float bf2f(unsigned short s) {
  return __uint_as_float(((unsigned int)s) << 16);
}

// -------------------------------------------------------------------------
// Transpose fp32 weight [K][256] -> bf16 [256][Kpad] (n-major, zero-padded K)
// -------------------------------------------------------------------------
__global__ __launch_bounds__(256) void transpose_bf16_kernel(
    const float* __restrict__ W, unsigned short* __restrict__ Wt,
    int K, int Kpad) {
  int idx = blockIdx.x * 256 + threadIdx.x;  // over 256*Kpad
  int n = idx / Kpad;
  int k = idx - n * Kpad;
  float v = (k < K) ? W[(size_t)k * H + n] : 0.f;
  Wt[idx] = f2bf(v);
}

// -------------------------------------------------------------------------
// Concat: Ac[N][160] bf16 = [x | gemb[gid] | 0-pad]
// -------------------------------------------------------------------------
__global__ __launch_bounds__(256) void concat_kernel(
    const float* __restrict__ x, const int* __restrict__ gid,
    const float* __restrict__ gemb, unsigned short* __restrict__ Ac,
    int F, int KP, int N) {
  int idx = blockIdx.x * 256 + threadIdx.x;  // over N*KP
  int n = idx / KP;
  int k = idx - n * KP;
  float v = 0.f;
  if (k < F) v = x[(size_t)n * F + k];
  else if (k < F + EMB) v = gemb[gid[n] * EMB + (k - F)];
  Ac[idx] = f2bf(v);
}

// -------------------------------------------------------------------------
// MFMA GEMM: C[N,256] = relu(A[N,K]bf16 @ B + bias), Bt is [256][K] bf16.
// 128x128 tile, 256 threads = 4 waves, each wave 64x64 via 4x4 of 16x16x32.
// -------------------------------------------------------------------------
template <int WRITE_BF16>
__global__ __launch_bounds__(256) void gemm_mfma_kernel(
    const unsigned short* __restrict__ A, const unsigned short* __restrict__ Bt,
    const float* __restrict__ bias, void* __restrict__ C, int N, int K) {
  const int m0 = blockIdx.y * 128;
  const int n0 = blockIdx.x * 128;
  const int tid = threadIdx.x;
  const int lane = tid & 63;
  const int wave = tid >> 6;
  const int wm = (wave & 1) * 64;
  const int wn = (wave >> 1) * 64;
  const int l16 = lane & 15;
  const int quad = lane >> 4;
  __shared__ __align__(16) unsigned short As[128][40];  // stride 80B: 2-way-max banks
  __shared__ __align__(16) unsigned short Bs[128][40];
  f32x4 acc[4][4] = {};
  // staging: 512 16B-chunks per tile (128 rows x 4), 2 chunks/thread each
  const int r0s = tid >> 2, c0s = tid & 3;          // chunk tid
  const int r1s = (tid + 256) >> 2, c1s = tid & 3;  // chunk tid+256
  for (int k0 = 0; k0 < K; k0 += 32) {
    __syncthreads();
    *(float4*)(&As[r0s][c0s * 8]) =
        *(const float4*)(A + (size_t)(m0 + r0s) * K + k0 + c0s * 8);
    *(float4*)(&As[r1s][c1s * 8]) =
        *(const float4*)(A + (size_t)(m0 + r1s) * K + k0 + c1s * 8);
    *(float4*)(&Bs[r0s][c0s * 8]) =
        *(const float4*)(Bt + (size_t)(n0 + r0s) * K + k0 + c0s * 8);
    *(float4*)(&Bs[r1s][c1s * 8]) =
        *(const float4*)(Bt + (size_t)(n0 + r1s) * K + k0 + c1s * 8);
    __syncthreads();
    short8 af[4], bf[4];
    #pragma unroll
    for (int i = 0; i < 4; ++i)
      af[i] = *(const short8*)(&As[wm + i * 16 + l16][quad * 8]);
    #pragma unroll
    for (int j = 0; j < 4; ++j)
      bf[j] = *(const short8*)(&Bs[wn + j * 16 + l16][quad * 8]);
    #pragma unroll
    for (int i = 0; i < 4; ++i)
      #pragma unroll
      for (int j = 0; j < 4; ++j)
        acc[i][j] = __builtin_amdgcn_mfma_f32_16x16x32_bf16(af[i], bf[j],
                                                            acc[i][j], 0, 0, 0);
  }
  #pragma unroll
  for (int j = 0; j < 4; ++j) {
    const int col = n0 + wn + j * 16 + l16;
    const float bj = bias[col];
    #pragma unroll
    for (int i = 0; i < 4; ++i) {
      #pragma unroll
      for (int r = 0; r < 4; ++r) {
        const int row = m0 + wm + i * 16 + quad * 4 + r;
        float v = fmaxf(acc[i][j][r] + bj, 0.f);
        if (WRITE_BF16)
          ((unsigned short*)C)[(size_t)row * H + col] = f2bf(v);
        else
          ((float*)C)[(size_t)row * H + col] = v;
      }
    }
  }
}

// -------------------------------------------------------------------------
// BatchNorm stats over h0 fp32
// -------------------------------------------------------------------------
__global__ __launch_bounds__(256) void bn_stats_kernel(
    const float* __restrict__ h0, float* __restrict__ stats, int N) {
  const int j = threadIdx.x;
  const int rpb = N >> 8;
  const int r0 = blockIdx.x * rpb;
  float s = 0.f, ss = 0.f;
  for (int r = 0; r < rpb; ++r) {
    float v = h0[(size_t)(r0 + r) * H + j];
    s += v;
    ss = fmaf(v, v, ss);
  }
  atomicAdd(&stats[j], s);
  atomicAdd(&stats[H + j], ss);
}

__global__ void bn_finalize_kernel(const float* __restrict__ gamma,
                                   const float* __restrict__ beta,
                                   float* __restrict__ stats, int N) {
  const int j = threadIdx.x;
  const float inv_n = 1.0f / (float)N;
  const float mu = stats[j] * inv_n;
  const float var = stats[H + j] * inv_n - mu * mu;
  const float rs = 1.0f / sqrtf(var + BN_EPS);
  const float a = gamma[j] * rs;
  stats[2 * H + j] = a;
  stats[3 * H + j] = beta[j] - mu * a;
}

// hbn[n][c] = bf16(a[c]*h0[n][c]+b[c])
__global__ __launch_bounds__(256) void hbn_kernel(
    const float* __restrict__ h0, const float* __restrict__ stats,
    unsigned short* __restrict__ hbn) {
  const int i = blockIdx.x * 256 + threadIdx.x;  // float4 group
  const int c = (i & 63) * 4;
  const float4 h = *(const float4*)(h0 + (size_t)i * 4);
  const float4 a = *(const float4*)(stats + 2 * H + c);
  const float4 b = *(const float4*)(stats + 3 * H + c);
  uint2 o;
  o.x = (unsigned int)f2bf(fmaf(a.x, h.x, b.x)) |
        ((unsigned int)f2bf(fmaf(a.y, h.y, b.y)) << 16);
  o.y = (unsigned int)f2bf(fmaf(a.z, h.z, b.z)) |
        ((unsigned int)f2bf(fmaf(a.w, h.w, b.w)) << 16);
  *(uint2*)(hbn + (size_t)i * 4) = o;
}

// -------------------------------------------------------------------------
// CSR build
// -------------------------------------------------------------------------
__global__ __launch_bounds__(256) void csr_count_kernel(
    const int* __restrict__ ei, int* __restrict__ deg, int E) {
  int e = blockIdx.x * 256 + threadIdx.x;
  if (e < E) atomicAdd(&deg[ei[E + e]], 1);
}

__global__ __launch_bounds__(1024) void scan_kernel(
    const int* __restrict__ deg, int* __restrict__ row_start,
    int* __restrict__ cursor, int n) {
  __shared__ int warp_sums[16];
  __shared__ int s_carry;
  const int lane = threadIdx.x & 63;
  const int wid = threadIdx.x >> 6;
  if (threadIdx.x == 0) s_carry = 0;
  __syncthreads();
  for (int base = 0; base < n; base += 1024) {
    int i = base + threadIdx.x;
    int v = (i < n) ? deg[i] : 0;
    int xi = v;
    #pragma unroll
    for (int d = 1; d < 64; d <<= 1) {
      int y = __shfl_up(xi, d, 64);
      if (lane >= d) xi += y;
    }
    if (lane == 63) warp_sums[wid] = xi;
    __syncthreads();
    if (wid == 0 && lane < 16) {
      int ws = warp_sums[lane];
      #pragma unroll
      for (int d = 1; d < 16; d <<= 1) {
        int y = __shfl_up(ws, d, 16);
        if (lane >= d) ws += y;
      }
      warp_sums[lane] = ws;
    }
    __syncthreads();
    int wave_off = (wid == 0) ? 0 : warp_sums[wid - 1];
    int excl = s_carry + wave_off + (xi - v);
    int total = warp_sums[15];
    if (i < n) {
      row_start[i] = excl;
      cursor[i] = excl;
    }
    __syncthreads();
    if (threadIdx.x == 0) s_carry += total;
    __syncthreads();
  }
  if (threadIdx.x == 0) row_start[n] = s_carry;
}

__global__ __launch_bounds__(256) void csr_scatter_kernel(
    const int* __restrict__ ei, int* __restrict__ cursor,
    int* __restrict__ csr_eid, int E) {
  int e = blockIdx.x * 256 + threadIdx.x;
  if (e < E) {
    int d = ei[E + e];
    int p = atomicAdd(&cursor[d], 1);
    csr_eid[p] = e;
  }
}

// -------------------------------------------------------------------------
// GINE aggregation: one wave per destination node, gather bf16 hbn,
// z (bf16) = hbn[n] + sum relu(hbn[src] + ea@We + be)
// -------------------------------------------------------------------------
__global__ __launch_bounds__(256) void aggregate_kernel(
    const unsigned short* __restrict__ hbn, const int* __restrict__ ei,
    const float* __restrict__ ea, const float* __restrict__ We,
    const float* __restrict__ be, const int* __restrict__ row_start,
    const int* __restrict__ csr_eid, unsigned short* __restrict__ z,
    int N, int E) {
  const int lane = threadIdx.x & 63;
  const int n = blockIdx.x * 4 + (threadIdx.x >> 6);
  if (n >= N) return;
  const int c = lane * 4;
  const float4 be4 = *(const float4*)(be + c);
  const float4 w0 = *(const float4*)(We + 0 * H + c);
  const float4 w1 = *(const float4*)(We + 1 * H + c);
  const float4 w2 = *(const float4*)(We + 2 * H + c);
  const float4 w3 = *(const float4*)(We + 3 * H + c);
  const float4 w4 = *(const float4*)(We + 4 * H + c);
  float4 agg = make_float4(0.f, 0.f, 0.f, 0.f);
  const int s0 = row_start[n], s1 = row_start[n + 1];
  for (int i = s0; i < s1; ++i) {
    const int e = csr_eid[i];
    const int src = ei[e];
    const float* eap = ea + (size_t)e * ED;
    const float e0 = eap[0], e1 = eap[1], e2 = eap[2], e3 = eap[3], e4 = eap[4];
    const uint2 hv = *(const uint2*)(hbn + (size_t)src * H + c);
    float mx = __uint_as_float(hv.x << 16) + be4.x;
    float my = __uint_as_float(hv.x & 0xffff0000u) + be4.y;
    float mz = __uint_as_float(hv.y << 16) + be4.z;
    float mw = __uint_as_float(hv.y & 0xffff0000u) + be4.w;
    mx = fmaf(e0, w0.x, mx); my = fmaf(e0, w0.y, my); mz = fmaf(e0, w0.z, mz); mw = fmaf(e0, w0.w, mw);
    mx = fmaf(e1, w1.x, mx); my = fmaf(e1, w1.y, my); mz = fmaf(e1, w1.z, mz); mw = fmaf(e1, w1.w, mw);
    mx = fmaf(e2, w2.x, mx); my = fmaf(e2, w2.y, my); mz = fmaf(e2, w2.z, mz); mw = fmaf(e2, w2.w, mw);
    mx = fmaf(e3, w3.x, mx); my = fmaf(e3, w3.y, my); mz = fmaf(e3, w3.z, mz); mw = fmaf(e3, w3.w, mw);
    mx = fmaf(e4, w4.x, mx); my = fmaf(e4, w4.y, my); mz = fmaf(e4, w4.z, mz); mw = fmaf(e4, w4.w, mw);
    agg.x += fmaxf(mx, 0.f);
    agg.y += fmaxf(my, 0.f);
    agg.z += fmaxf(mz, 0.f);
    agg.w += fmaxf(mw, 0.f);
  }
  const uint2 hs = *(const uint2*)(hbn + (size_t)n * H + c);
  float zx = __uint_as_float(hs.x << 16) + agg.x;
  float zy = __uint_as_float(hs.x & 0xffff0000u) + agg.y;
  float zz = __uint_as_float(hs.y << 16) + agg.z;
  float zw = __uint_as_float(hs.y & 0xffff0000u) + agg.w;
  uint2 o;
  o.x = (unsigned int)f2bf(zx) | ((unsigned int)f2bf(zy) << 16);
  o.y = (unsigned int)f2bf(zz) | ((unsigned int)f2bf(zw) << 16);
  *(uint2*)(z + (size_t)n * H + c) = o;
}

// -------------------------------------------------------------------------
extern "C" void kernel_launch(void* const* d_in, const int* in_sizes, int n_in,
                              void* d_out, int out_size, void* d_ws, size_t ws_size,
                              hipStream_t stream) {
  const float* x     = (const float*)d_in[0];
  const int*   ei    = (const int*)d_in[1];
  const float* ea    = (const float*)d_in[2];
  const int*   gid   = (const int*)d_in[3];
  const float* gemb  = (const float*)d_in[4];
  const float* W_in  = (const float*)d_in[5];
  const float* b_in  = (const float*)d_in[6];
  const float* gamma = (const float*)d_in[7];
  const float* beta  = (const float*)d_in[8];
  const float* We    = (const float*)d_in[9];
  const float* be    = (const float*)d_in[10];
  const float* W1    = (const float*)d_in[11];
  const float* b1    = (const float*)d_in[12];
  const float* W2    = (const float*)d_in[13];
  const float* b2    = (const float*)d_in[14];
  float* out = (float*)d_out;

  const int N = in_sizes[3];       // 59392
  const int E = in_sizes[1] / 2;   // 950272
  const int F = in_sizes[0] / N;   // 116
  const int KP = 160;              // padded K for input gemm (F+EMB=132 -> 160)

  // ---- workspace layout (256B-aligned segments) ----
  char* p = (char*)d_ws;
  auto take = [&](size_t bytes) {
    char* r = p;
    p += (bytes + 255) & ~(size_t)255;
    return r;
  };
  float* stats          = (float*)take(1024 * sizeof(float));
  int* deg              = (int*)take((size_t)N * 4);
  int* row_start        = (int*)take((size_t)(N + 1) * 4);
  int* cursor           = (int*)take((size_t)N * 4);
  int* csr_eid          = (int*)take((size_t)E * 4);
  unsigned short* Wtin  = (unsigned short*)take((size_t)H * KP * 2);
  unsigned short* Wt1   = (unsigned short*)take((size_t)H * H * 2);
  unsigned short* Wt2   = (unsigned short*)take((size_t)H * H * 2);
  unsigned short* Ac    = (unsigned short*)take((size_t)N * KP * 2);
  unsigned short* hbn   = (unsigned short*)take((size_t)N * H * 2);
  float* h0             = (float*)take((size_t)N * H * 4);
  unsigned short* z     = (unsigned short*)h0;                    // reuse (h0 dead)
  unsigned short* hid   = (unsigned short*)h0 + (size_t)N * H;    // second half

  // zero BN accumulators + degree histogram (stats and deg are adjacent)
  hipMemsetAsync(stats, 0, (size_t)(1024 + N) * 4 + 256, stream);

  // weight prep
  transpose_bf16_kernel<<<(H * KP) / 256, 256, 0, stream>>>(W_in, Wtin, F + EMB, KP);
  transpose_bf16_kernel<<<(H * H) / 256, 256, 0, stream>>>(W1, Wt1, H, H);
  transpose_bf16_kernel<<<(H * H) / 256, 256, 0, stream>>>(W2, Wt2, H, H);

  // CSR build (independent)
  csr_count_kernel<<<(E + 255) / 256, 256, 0, stream>>>(ei, deg, E);
  scan_kernel<<<1, 1024, 0, stream>>>(deg, row_start, cursor, N);
  csr_scatter_kernel<<<(E + 255) / 256, 256, 0, stream>>>(ei, cursor, csr_eid, E);

  // input layer
  concat_kernel<<<((size_t)N * KP) / 256, 256, 0, stream>>>(x, gid, gemb, Ac, F, KP, N);
  dim3 ggrid(H / 128, N / 128);
  gemm_mfma_kernel<0><<<ggrid, 256, 0, stream>>>(Ac, Wtin, b_in, h0, N, KP);

  // batchnorm
  bn_stats_kernel<<<256, 256, 0, stream>>>(h0, stats, N);
  bn_finalize_kernel<<<1, 256, 0, stream>>>(gamma, beta, stats, N);
  hbn_kernel<<<((size_t)N * H / 4) / 256, 256, 0, stream>>>(h0, stats, hbn);

  // GINE aggregate -> z (bf16)
  aggregate_kernel<<<(N + 3) / 4, 256, 0, stream>>>(hbn, ei, ea, We, be,
                                                    row_start, csr_eid, z, N, E);

  // MLP
  gemm_mfma_kernel<1><<<ggrid, 256, 0, stream>>>(z, Wt1, b1, hid, N, H);
  gemm_mfma_kernel<0><<<ggrid, 256, 0, stream>>>(hid, Wt2, b2, out, N, H);

  // passthrough second output: edge_attr
  hipMemcpyAsync(out + (size_t)N * H, ea, (size_t)E * ED * sizeof(float),
                 hipMemcpyDeviceToDevice, stream);
}

// Round 3
// 528.949 us; speedup vs baseline: 1.6369x; 1.2519x over previous
//
#include <hip/hip_runtime.h>
#include <hip/hip_bf16.h>
#include <cstdint>
#include <cstddef>

#define H 256
#define EMB 16
#define ED 5
#define KP 160
#define BN_EPS 1e-5f

typedef __attribute__((ext_vector_type(8))) short short8;
typedef __attribute__((ext_vector_type(4))) float f32x4;

__device__ __forceinline__ unsigned short f2bf(float f) {
  unsigned int u = __float_as_uint(f);
  unsigned int r = (u + 0x7fffu + ((u >> 16) & 1u)) >> 16;
  return (unsigned short)r;
}
__device__ __forceinline__ float bfhi(unsigned int u) {  // high 16 bits as bf16
  return __uint_as_float(u & 0xffff0000u);
}
__device__ __forceinline__ float bflo(unsigned int u) {  // low 16 bits as bf16
  return __uint_as_float(u << 16);
}

// -------------------------------------------------------------------------
// Weight prep (single kernel): transpose all three fp32 [K][256] weights to
// bf16 [256][Kpad] n-major.  Segments: W_in (KP=160), W1 (256), W2 (256).
// -------------------------------------------------------------------------
__global__ __launch_bounds__(256) void prep_weights_kernel(
    const float* __restrict__ Win, const float* __restrict__ W1,
    const float* __restrict__ W2, unsigned short* __restrict__ Wtin,
    unsigned short* __restrict__ Wt1, unsigned short* __restrict__ Wt2,
    int Kin) {
  int idx = blockIdx.x * 256 + threadIdx.x;
  if (idx < H * KP) {
    int n = idx / KP, k = idx - n * KP;
    Wtin[idx] = f2bf((k < Kin) ? Win[(size_t)k * H + n] : 0.f);
  } else if (idx < H * KP + H * H) {
    int i2 = idx - H * KP;
    int n = i2 >> 8, k = i2 & 255;
    Wt1[i2] = f2bf(W1[(size_t)k * H + n]);
  } else {
    int i2 = idx - H * KP - H * H;
    int n = i2 >> 8, k = i2 & 255;
    Wt2[i2] = f2bf(W2[(size_t)k * H + n]);
  }
}

// -------------------------------------------------------------------------
// Concat: Ac[N][160] bf16 = [x | gemb[gid] | 0-pad]
// -------------------------------------------------------------------------
__global__ __launch_bounds__(256) void concat_kernel(
    const float* __restrict__ x, const int* __restrict__ gid,
    const float* __restrict__ gemb, unsigned short* __restrict__ Ac,
    int F, int N) {
  int idx = blockIdx.x * 256 + threadIdx.x;  // over N*KP
  int n = idx / KP;
  int k = idx - n * KP;
  float v = 0.f;
  if (k < F) v = x[(size_t)n * F + k];
  else if (k < F + EMB) v = gemb[gid[n] * EMB + (k - F)];
  Ac[idx] = f2bf(v);
}

// -------------------------------------------------------------------------
// MFMA GEMM: C = relu(A[N,K]bf16 @ B + bias); Bt is [256][K] bf16.
// 128x128 tile, 4 waves, 4x4 of 16x16x32 each.
// -------------------------------------------------------------------------
template <int WRITE_BF16>
__global__ __launch_bounds__(256) void gemm_mfma_kernel(
    const unsigned short* __restrict__ A, const unsigned short* __restrict__ Bt,
    const float* __restrict__ bias, void* __restrict__ C, int N, int K) {
  const int m0 = blockIdx.y * 128;
  const int n0 = blockIdx.x * 128;
  const int tid = threadIdx.x;
  const int lane = tid & 63;
  const int wave = tid >> 6;
  const int wm = (wave & 1) * 64;
  const int wn = (wave >> 1) * 64;
  const int l16 = lane & 15;
  const int quad = lane >> 4;
  __shared__ __align__(16) unsigned short As[128][40];
  __shared__ __align__(16) unsigned short Bs[128][40];
  f32x4 acc[4][4] = {};
  const int r0s = tid >> 2, c0s = tid & 3;
  const int r1s = (tid + 256) >> 2;
  for (int k0 = 0; k0 < K; k0 += 32) {
    __syncthreads();
    *(float4*)(&As[r0s][c0s * 8]) =
        *(const float4*)(A + (size_t)(m0 + r0s) * K + k0 + c0s * 8);
    *(float4*)(&As[r1s][c0s * 8]) =
        *(const float4*)(A + (size_t)(m0 + r1s) * K + k0 + c0s * 8);
    *(float4*)(&Bs[r0s][c0s * 8]) =
        *(const float4*)(Bt + (size_t)(n0 + r0s) * K + k0 + c0s * 8);
    *(float4*)(&Bs[r1s][c0s * 8]) =
        *(const float4*)(Bt + (size_t)(n0 + r1s) * K + k0 + c0s * 8);
    __syncthreads();
    short8 af[4], bf[4];
    #pragma unroll
    for (int i = 0; i < 4; ++i)
      af[i] = *(const short8*)(&As[wm + i * 16 + l16][quad * 8]);
    #pragma unroll
    for (int j = 0; j < 4; ++j)
      bf[j] = *(const short8*)(&Bs[wn + j * 16 + l16][quad * 8]);
    #pragma unroll
    for (int i = 0; i < 4; ++i)
      #pragma unroll
      for (int j = 0; j < 4; ++j)
        acc[i][j] = __builtin_amdgcn_mfma_f32_16x16x32_bf16(af[i], bf[j],
                                                            acc[i][j], 0, 0, 0);
  }
  #pragma unroll
  for (int j = 0; j < 4; ++j) {
    const int col = n0 + wn + j * 16 + l16;
    const float bj = bias[col];
    #pragma unroll
    for (int i = 0; i < 4; ++i) {
      #pragma unroll
      for (int r = 0; r < 4; ++r) {
        const int row = m0 + wm + i * 16 + quad * 4 + r;
        float v = fmaxf(acc[i][j][r] + bj, 0.f);
        if (WRITE_BF16)
          ((unsigned short*)C)[(size_t)row * H + col] = f2bf(v);
        else
          ((float*)C)[(size_t)row * H + col] = v;
      }
    }
  }
}

// -------------------------------------------------------------------------
// BatchNorm stats over bf16 h0: per-column sum / sumsq
// -------------------------------------------------------------------------
__global__ __launch_bounds__(256) void bn_stats_kernel(
    const unsigned short* __restrict__ h0, float* __restrict__ stats, int N) {
  const int j = threadIdx.x;
  const int rpb = N >> 8;
  const int r0 = blockIdx.x * rpb;
  float s = 0.f, ss = 0.f;
  for (int r = 0; r < rpb; ++r) {
    float v = bflo(h0[(size_t)(r0 + r) * H + j]);
    s += v;
    ss = fmaf(v, v, ss);
  }
  atomicAdd(&stats[j], s);
  atomicAdd(&stats[H + j], ss);
}

// -------------------------------------------------------------------------
// hbn = bf16(a*h0+b), with BN finalize folded in (per-block recompute)
// -------------------------------------------------------------------------
__global__ __launch_bounds__(256) void hbn_kernel(
    const unsigned short* __restrict__ h0, const float* __restrict__ stats,
    const float* __restrict__ gamma, const float* __restrict__ beta,
    unsigned short* __restrict__ hbn, float inv_n) {
  __shared__ float sa[H], sb[H];
  {
    const int j = threadIdx.x;
    const float mu = stats[j] * inv_n;
    const float var = stats[H + j] * inv_n - mu * mu;
    const float rs = 1.0f / sqrtf(var + BN_EPS);
    const float a = gamma[j] * rs;
    sa[j] = a;
    sb[j] = beta[j] - mu * a;
  }
  __syncthreads();
  const size_t i = (size_t)blockIdx.x * 256 + threadIdx.x;  // uint4 groups
  const int c = ((int)(i & 31)) * 8;
  const uint4 hv = ((const uint4*)h0)[i];
  float r[8] = {bflo(hv.x), bfhi(hv.x), bflo(hv.y), bfhi(hv.y),
                bflo(hv.z), bfhi(hv.z), bflo(hv.w), bfhi(hv.w)};
  unsigned short o[8];
  #pragma unroll
  for (int t = 0; t < 8; ++t)
    o[t] = f2bf(fmaf(sa[c + t], r[t], sb[c + t]));
  uint4 ov;
  ov.x = (unsigned)o[0] | ((unsigned)o[1] << 16);
  ov.y = (unsigned)o[2] | ((unsigned)o[3] << 16);
  ov.z = (unsigned)o[4] | ((unsigned)o[5] << 16);
  ov.w = (unsigned)o[6] | ((unsigned)o[7] << 16);
  ((uint4*)hbn)[i] = ov;
}

// -------------------------------------------------------------------------
// CSR build: count -> scan -> scatter fused 16B edge records {src, ea[5]bf16}
// -------------------------------------------------------------------------
__global__ __launch_bounds__(256) void csr_count_kernel(
    const int* __restrict__ ei, int* __restrict__ deg, int E) {
  int e = blockIdx.x * 256 + threadIdx.x;
  if (e < E) atomicAdd(&deg[ei[E + e]], 1);
}

__global__ __launch_bounds__(1024) void scan_kernel(
    const int* __restrict__ deg, int* __restrict__ row_start,
    int* __restrict__ cursor, int n) {
  __shared__ int warp_sums[16];
  __shared__ int s_carry;
  const int lane = threadIdx.x & 63;
  const int wid = threadIdx.x >> 6;
  if (threadIdx.x == 0) s_carry = 0;
  __syncthreads();
  for (int base = 0; base < n; base += 1024) {
    int i = base + threadIdx.x;
    int v = (i < n) ? deg[i] : 0;
    int xi = v;
    #pragma unroll
    for (int d = 1; d < 64; d <<= 1) {
      int y = __shfl_up(xi, d, 64);
      if (lane >= d) xi += y;
    }
    if (lane == 63) warp_sums[wid] = xi;
    __syncthreads();
    if (wid == 0 && lane < 16) {
      int ws = warp_sums[lane];
      #pragma unroll
      for (int d = 1; d < 16; d <<= 1) {
        int y = __shfl_up(ws, d, 16);
        if (lane >= d) ws += y;
      }
      warp_sums[lane] = ws;
    }
    __syncthreads();
    int wave_off = (wid == 0) ? 0 : warp_sums[wid - 1];
    int excl = s_carry + wave_off + (xi - v);
    int total = warp_sums[15];
    if (i < n) {
      row_start[i] = excl;
      cursor[i] = excl;
    }
    __syncthreads();
    if (threadIdx.x == 0) s_carry += total;
    __syncthreads();
  }
  if (threadIdx.x == 0) row_start[n] = s_carry;
}

__global__ __launch_bounds__(256) void csr_scatter_kernel(
    const int* __restrict__ ei, const float* __restrict__ ea,
    int* __restrict__ cursor, uint4* __restrict__ rec, int E) {
  int e = blockIdx.x * 256 + threadIdx.x;
  if (e >= E) return;
  int s = ei[e];
  int d = ei[E + e];
  int p = atomicAdd(&cursor[d], 1);
  const float* eap = ea + (size_t)e * ED;
  unsigned b0 = f2bf(eap[0]), b1 = f2bf(eap[1]), b2 = f2bf(eap[2]);
  unsigned b3 = f2bf(eap[3]), b4 = f2bf(eap[4]);
  uint4 r;
  r.x = (unsigned)s;
  r.y = b0 | (b1 << 16);
  r.z = b2 | (b3 << 16);
  r.w = b4;
  rec[p] = r;
}

// -------------------------------------------------------------------------
// GINE aggregation: wave per node, fused records, 4x edge unroll.
// z(bf16) = hbn[n] + sum relu(hbn[src] + ea@We + be)
// -------------------------------------------------------------------------
__device__ __forceinline__ void edge_accum(
    const uint4 rr, const uint2 hv, const float4 w0, const float4 w1,
    const float4 w2, const float4 w3, const float4 w4, const float4 be4,
    float4& agg) {
  const float e0 = bflo(rr.y), e1 = bfhi(rr.y);
  const float e2 = bflo(rr.z), e3 = bfhi(rr.z);
  const float e4 = bflo(rr.w);
  float mx = bflo(hv.x) + be4.x;
  float my = bfhi(hv.x) + be4.y;
  float mz = bflo(hv.y) + be4.z;
  float mw = bfhi(hv.y) + be4.w;
  mx = fmaf(e0, w0.x, mx); my = fmaf(e0, w0.y, my); mz = fmaf(e0, w0.z, mz); mw = fmaf(e0, w0.w, mw);
  mx = fmaf(e1, w1.x, mx); my = fmaf(e1, w1.y, my); mz = fmaf(e1, w1.z, mz); mw = fmaf(e1, w1.w, mw);
  mx = fmaf(e2, w2.x, mx); my = fmaf(e2, w2.y, my); mz = fmaf(e2, w2.z, mz); mw = fmaf(e2, w2.w, mw);
  mx = fmaf(e3, w3.x, mx); my = fmaf(e3, w3.y, my); mz = fmaf(e3, w3.z, mz); mw = fmaf(e3, w3.w, mw);
  mx = fmaf(e4, w4.x, mx); my = fmaf(e4, w4.y, my); mz = fmaf(e4, w4.z, mz); mw = fmaf(e4, w4.w, mw);
  agg.x += fmaxf(mx, 0.f);
  agg.y += fmaxf(my, 0.f);
  agg.z += fmaxf(mz, 0.f);
  agg.w += fmaxf(mw, 0.f);
}

__global__ __launch_bounds__(256) void aggregate_kernel(
    const unsigned short* __restrict__ hbn, const uint4* __restrict__ rec,
    const float* __restrict__ We, const float* __restrict__ be,
    const int* __restrict__ row_start, unsigned short* __restrict__ z,
    int N) {
  const int lane = threadIdx.x & 63;
  int n = blockIdx.x * 4 + (threadIdx.x >> 6);
  if (n >= N) return;
  n = __builtin_amdgcn_readfirstlane(n);  // wave-uniform -> scalar pipe
  const int c = lane * 4;
  const float4 be4 = *(const float4*)(be + c);
  const float4 w0 = *(const float4*)(We + 0 * H + c);
  const float4 w1 = *(const float4*)(We + 1 * H + c);
  const float4 w2 = *(const float4*)(We + 2 * H + c);
  const float4 w3 = *(const float4*)(We + 3 * H + c);
  const float4 w4 = *(const float4*)(We + 4 * H + c);
  float4 agg = make_float4(0.f, 0.f, 0.f, 0.f);
  const int s0 = __builtin_amdgcn_readfirstlane(row_start[n]);
  const int s1 = __builtin_amdgcn_readfirstlane(row_start[n + 1]);
  const uint4* rp = rec + s0;
  const int cnt = s1 - s0;
  int i = 0;
  for (; i + 4 <= cnt; i += 4) {
    const uint4 r0 = rp[i + 0];
    const uint4 r1 = rp[i + 1];
    const uint4 r2 = rp[i + 2];
    const uint4 r3 = rp[i + 3];
    const uint2 h0v = *(const uint2*)(hbn + (size_t)(int)r0.x * H + c);
    const uint2 h1v = *(const uint2*)(hbn + (size_t)(int)r1.x * H + c);
    const uint2 h2v = *(const uint2*)(hbn + (size_t)(int)r2.x * H + c);
    const uint2 h3v = *(const uint2*)(hbn + (size_t)(int)r3.x * H + c);
    edge_accum(r0, h0v, w0, w1, w2, w3, w4, be4, agg);
    edge_accum(r1, h1v, w0, w1, w2, w3, w4, be4, agg);
    edge_accum(r2, h2v, w0, w1, w2, w3, w4, be4, agg);
    edge_accum(r3, h3v, w0, w1, w2, w3, w4, be4, agg);
  }
  for (; i < cnt; ++i) {
    const uint4 r0 = rp[i];
    const uint2 h0v = *(const uint2*)(hbn + (size_t)(int)r0.x * H + c);
    edge_accum(r0, h0v, w0, w1, w2, w3, w4, be4, agg);
  }
  const uint2 hs = *(const uint2*)(hbn + (size_t)n * H + c);
  float zx = bflo(hs.x) + agg.x;
  float zy = bfhi(hs.x) + agg.y;
  float zz = bflo(hs.y) + agg.z;
  float zw = bfhi(hs.y) + agg.w;
  uint2 o;
  o.x = (unsigned)f2bf(zx) | ((unsigned)f2bf(zy) << 16);
  o.y = (unsigned)f2bf(zz) | ((unsigned)f2bf(zw) << 16);
  *(uint2*)(z + (size_t)n * H + c) = o;
}

// -------------------------------------------------------------------------
extern "C" void kernel_launch(void* const* d_in, const int* in_sizes, int n_in,
                              void* d_out, int out_size, void* d_ws, size_t ws_size,
                              hipStream_t stream) {
  const float* x     = (const float*)d_in[0];
  const int*   ei    = (const int*)d_in[1];
  const float* ea    = (const float*)d_in[2];
  const int*   gid   = (const int*)d_in[3];
  const float* gemb  = (const float*)d_in[4];
  const float* W_in  = (const float*)d_in[5];
  const float* b_in  = (const float*)d_in[6];
  const float* gamma = (const float*)d_in[7];
  const float* beta  = (const float*)d_in[8];
  const float* We    = (const float*)d_in[9];
  const float* be    = (const float*)d_in[10];
  const float* W1    = (const float*)d_in[11];
  const float* b1    = (const float*)d_in[12];
  const float* W2    = (const float*)d_in[13];
  const float* b2    = (const float*)d_in[14];
  float* out = (float*)d_out;

  const int N = in_sizes[3];       // 59392
  const int E = in_sizes[1] / 2;   // 950272
  const int F = in_sizes[0] / N;   // 116

  // ---- workspace layout ----
  char* p = (char*)d_ws;
  auto take = [&](size_t bytes) {
    char* r = p;
    p += (bytes + 255) & ~(size_t)255;
    return r;
  };
  float* stats          = (float*)take(1024 * sizeof(float));
  int* deg              = (int*)take((size_t)N * 4);
  int* row_start        = (int*)take((size_t)(N + 1) * 4);
  int* cursor           = (int*)take((size_t)N * 4);
  uint4* rec            = (uint4*)take((size_t)E * 16);
  unsigned short* Wtin  = (unsigned short*)take((size_t)H * KP * 2);
  unsigned short* Wt1   = (unsigned short*)take((size_t)H * H * 2);
  unsigned short* Wt2   = (unsigned short*)take((size_t)H * H * 2);
  unsigned short* Ac    = (unsigned short*)take((size_t)N * KP * 2);
  unsigned short* h0    = (unsigned short*)take((size_t)N * H * 2);
  unsigned short* hbn   = (unsigned short*)take((size_t)N * H * 2);
  unsigned short* z     = (unsigned short*)take((size_t)N * H * 2);
  unsigned short* hid   = (unsigned short*)take((size_t)N * H * 2);

  // zero BN accumulators + degree histogram (contiguous: stats pad=4096 then deg)
  hipMemsetAsync(stats, 0, 4096 + (size_t)N * 4, stream);

  // weight prep (1 kernel for all 3)
  prep_weights_kernel<<<(H * KP + 2 * H * H) / 256, 256, 0, stream>>>(
      W_in, W1, W2, Wtin, Wt1, Wt2, F + EMB);

  // CSR build with fused records
  csr_count_kernel<<<(E + 255) / 256, 256, 0, stream>>>(ei, deg, E);
  scan_kernel<<<1, 1024, 0, stream>>>(deg, row_start, cursor, N);
  csr_scatter_kernel<<<(E + 255) / 256, 256, 0, stream>>>(ei, ea, cursor, rec, E);

  // input layer -> bf16 h0
  concat_kernel<<<((size_t)N * KP) / 256, 256, 0, stream>>>(x, gid, gemb, Ac, F, N);
  dim3 ggrid(H / 128, N / 128);
  gemm_mfma_kernel<1><<<ggrid, 256, 0, stream>>>(Ac, Wtin, b_in, h0, N, KP);

  // batchnorm
  bn_stats_kernel<<<256, 256, 0, stream>>>(h0, stats, N);
  hbn_kernel<<<((size_t)N * H / 8) / 256, 256, 0, stream>>>(
      h0, stats, gamma, beta, hbn, 1.0f / (float)N);

  // GINE aggregate -> z (bf16)
  aggregate_kernel<<<(N + 3) / 4, 256, 0, stream>>>(hbn, rec, We, be,
                                                    row_start, z, N);

  // MLP
  gemm_mfma_kernel<1><<<ggrid, 256, 0, stream>>>(z, Wt1, b1, hid, N, H);
  gemm_mfma_kernel<0><<<ggrid, 256, 0, stream>>>(hid, Wt2, b2, out, N, H);

  // passthrough second output: edge_attr
  hipMemcpyAsync(out + (size_t)N * H, ea, (size_t)E * ED * sizeof(float),
                 hipMemcpyDeviceToDevice, stream);
}

// Round 5
// 480.440 us; speedup vs baseline: 1.8022x; 1.1010x over previous
//
#include <hip/hip_runtime.h>
#include <hip/hip_bf16.h>
#include <cstdint>
#include <cstddef>

#define H 256
#define EMB 16
#define ED 5
#define KP 160
#define BN_EPS 1e-5f

typedef __attribute__((ext_vector_type(8))) short short8;
typedef __attribute__((ext_vector_type(4))) float f32x4;
typedef _Float16 h2 __attribute__((ext_vector_type(2)));

__device__ __forceinline__ unsigned short f2bf(float f) {
  unsigned int u = __float_as_uint(f);
  unsigned int r = (u + 0x7fffu + ((u >> 16) & 1u)) >> 16;
  return (unsigned short)r;
}
__device__ __forceinline__ float bfhi(unsigned int u) {
  return __uint_as_float(u & 0xffff0000u);
}
__device__ __forceinline__ float bflo(unsigned int u) {
  return __uint_as_float(u << 16);
}
__device__ __forceinline__ h2 u2h2(unsigned int u) {
  union { unsigned int u; h2 h; } c;
  c.u = u;
  return c.h;
}
__device__ __forceinline__ unsigned int h22u(h2 h) {
  union { h2 h; unsigned int u; } c;
  c.h = h;
  return c.u;
}
__device__ __forceinline__ h2 mkh2(float a, float b) {
  h2 r;
  r.x = (_Float16)a;
  r.y = (_Float16)b;
  return r;
}

// -------------------------------------------------------------------------
// Weight prep: transpose three fp32 [K][256] weights to bf16 [256][Kpad]
// -------------------------------------------------------------------------
__global__ __launch_bounds__(256) void prep_weights_kernel(
    const float* __restrict__ Win, const float* __restrict__ W1,
    const float* __restrict__ W2, unsigned short* __restrict__ Wtin,
    unsigned short* __restrict__ Wt1, unsigned short* __restrict__ Wt2,
    int Kin) {
  int idx = blockIdx.x * 256 + threadIdx.x;
  if (idx < H * KP) {
    int n = idx / KP, k = idx - n * KP;
    Wtin[idx] = f2bf((k < Kin) ? Win[(size_t)k * H + n] : 0.f);
  } else if (idx < H * KP + H * H) {
    int i2 = idx - H * KP;
    int n = i2 >> 8, k = i2 & 255;
    Wt1[i2] = f2bf(W1[(size_t)k * H + n]);
  } else {
    int i2 = idx - H * KP - H * H;
    int n = i2 >> 8, k = i2 & 255;
    Wt2[i2] = f2bf(W2[(size_t)k * H + n]);
  }
}

// -------------------------------------------------------------------------
// Concat: Ac[N][160] bf16 = [x | gemb[gid] | 0-pad]
// -------------------------------------------------------------------------
__global__ __launch_bounds__(256) void concat_kernel(
    const float* __restrict__ x, const int* __restrict__ gid,
    const float* __restrict__ gemb, unsigned short* __restrict__ Ac,
    int F, int N) {
  int idx = blockIdx.x * 256 + threadIdx.x;
  int n = idx / KP;
  int k = idx - n * KP;
  float v = 0.f;
  if (k < F) v = x[(size_t)n * F + k];
  else if (k < F + EMB) v = gemb[gid[n] * EMB + (k - F)];
  Ac[idx] = f2bf(v);
}

// -------------------------------------------------------------------------
// MFMA GEMM: C = relu(A[N,K]bf16 @ B + bias); Bt is [256][K] bf16.
// -------------------------------------------------------------------------
template <int WRITE_BF16>
__global__ __launch_bounds__(256) void gemm_mfma_kernel(
    const unsigned short* __restrict__ A, const unsigned short* __restrict__ Bt,
    const float* __restrict__ bias, void* __restrict__ C, int N, int K) {
  const int m0 = blockIdx.y * 128;
  const int n0 = blockIdx.x * 128;
  const int tid = threadIdx.x;
  const int lane = tid & 63;
  const int wave = tid >> 6;
  const int wm = (wave & 1) * 64;
  const int wn = (wave >> 1) * 64;
  const int l16 = lane & 15;
  const int quad = lane >> 4;
  __shared__ __align__(16) unsigned short As[128][40];
  __shared__ __align__(16) unsigned short Bs[128][40];
  f32x4 acc[4][4] = {};
  const int r0s = tid >> 2, c0s = tid & 3;
  const int r1s = (tid + 256) >> 2;
  for (int k0 = 0; k0 < K; k0 += 32) {
    __syncthreads();
    *(float4*)(&As[r0s][c0s * 8]) =
        *(const float4*)(A + (size_t)(m0 + r0s) * K + k0 + c0s * 8);
    *(float4*)(&As[r1s][c0s * 8]) =
        *(const float4*)(A + (size_t)(m0 + r1s) * K + k0 + c0s * 8);
    *(float4*)(&Bs[r0s][c0s * 8]) =
        *(const float4*)(Bt + (size_t)(n0 + r0s) * K + k0 + c0s * 8);
    *(float4*)(&Bs[r1s][c0s * 8]) =
        *(const float4*)(Bt + (size_t)(n0 + r1s) * K + k0 + c0s * 8);
    __syncthreads();
    short8 af[4], bf[4];
    #pragma unroll
    for (int i = 0; i < 4; ++i)
      af[i] = *(const short8*)(&As[wm + i * 16 + l16][quad * 8]);
    #pragma unroll
    for (int j = 0; j < 4; ++j)
      bf[j] = *(const short8*)(&Bs[wn + j * 16 + l16][quad * 8]);
    #pragma unroll
    for (int i = 0; i < 4; ++i)
      #pragma unroll
      for (int j = 0; j < 4; ++j)
        acc[i][j] = __builtin_amdgcn_mfma_f32_16x16x32_bf16(af[i], bf[j],
                                                            acc[i][j], 0, 0, 0);
  }
  #pragma unroll
  for (int j = 0; j < 4; ++j) {
    const int col = n0 + wn + j * 16 + l16;
    const float bj = bias[col];
    #pragma unroll
    for (int i = 0; i < 4; ++i) {
      #pragma unroll
      for (int r = 0; r < 4; ++r) {
        const int row = m0 + wm + i * 16 + quad * 4 + r;
        float v = fmaxf(acc[i][j][r] + bj, 0.f);
        if (WRITE_BF16)
          ((unsigned short*)C)[(size_t)row * H + col] = f2bf(v);
        else
          ((float*)C)[(size_t)row * H + col] = v;
      }
    }
  }
}

// -------------------------------------------------------------------------
// BatchNorm stats over bf16 h0
// -------------------------------------------------------------------------
__global__ __launch_bounds__(256) void bn_stats_kernel(
    const unsigned short* __restrict__ h0, float* __restrict__ stats, int N) {
  const int j = threadIdx.x;
  const int rpb = N >> 8;
  const int r0 = blockIdx.x * rpb;
  float s = 0.f, ss = 0.f;
  for (int r = 0; r < rpb; ++r) {
    float v = bflo(h0[(size_t)(r0 + r) * H + j]);
    s += v;
    ss = fmaf(v, v, ss);
  }
  atomicAdd(&stats[j], s);
  atomicAdd(&stats[H + j], ss);
}

// -------------------------------------------------------------------------
// hbn(fp16) = a*h0+b with BN finalize folded in
// -------------------------------------------------------------------------
__global__ __launch_bounds__(256) void hbn_kernel(
    const unsigned short* __restrict__ h0, const float* __restrict__ stats,
    const float* __restrict__ gamma, const float* __restrict__ beta,
    unsigned short* __restrict__ hbn, float inv_n) {
  __shared__ float sa[H], sb[H];
  {
    const int j = threadIdx.x;
    const float mu = stats[j] * inv_n;
    const float var = stats[H + j] * inv_n - mu * mu;
    const float rs = 1.0f / sqrtf(var + BN_EPS);
    const float a = gamma[j] * rs;
    sa[j] = a;
    sb[j] = beta[j] - mu * a;
  }
  __syncthreads();
  const size_t i = (size_t)blockIdx.x * 256 + threadIdx.x;
  const int c = ((int)(i & 31)) * 8;
  const uint4 hv = ((const uint4*)h0)[i];
  float r[8] = {bflo(hv.x), bfhi(hv.x), bflo(hv.y), bfhi(hv.y),
                bflo(hv.z), bfhi(hv.z), bflo(hv.w), bfhi(hv.w)};
  float o[8];
  #pragma unroll
  for (int t = 0; t < 8; ++t)
    o[t] = fmaf(sa[c + t], r[t], sb[c + t]);
  uint4 ov;
  ov.x = h22u(mkh2(o[0], o[1]));
  ov.y = h22u(mkh2(o[2], o[3]));
  ov.z = h22u(mkh2(o[4], o[5]));
  ov.w = h22u(mkh2(o[6], o[7]));
  ((uint4*)hbn)[i] = ov;
}

// -------------------------------------------------------------------------
// CSR build: count -> 3-phase scan -> scatter {src, ea[5]fp16} records
// -------------------------------------------------------------------------
__global__ __launch_bounds__(256) void csr_count_kernel(
    const int* __restrict__ ei, int* __restrict__ deg, int E) {
  int e = blockIdx.x * 256 + threadIdx.x;
  if (e < E) atomicAdd(&deg[ei[E + e]], 1);
}

__global__ __launch_bounds__(256) void scan_blocks_kernel(
    const int* __restrict__ deg, int* __restrict__ excl,
    int* __restrict__ bsums, int n) {
  const int tid = threadIdx.x;
  const int i = blockIdx.x * 256 + tid;
  const int lane = tid & 63, wid = tid >> 6;
  int v = (i < n) ? deg[i] : 0;
  int x = v;
  #pragma unroll
  for (int d = 1; d < 64; d <<= 1) {
    int y = __shfl_up(x, d, 64);
    if (lane >= d) x += y;
  }
  __shared__ int ws[4], wo[4];
  if (lane == 63) ws[wid] = x;
  __syncthreads();
  if (tid == 0) {
    int a = 0;
    #pragma unroll
    for (int w = 0; w < 4; ++w) { wo[w] = a; a += ws[w]; }
    bsums[blockIdx.x] = a;
  }
  __syncthreads();
  if (i < n) excl[i] = x - v + wo[wid];
}

__global__ __launch_bounds__(256) void scan_sums_kernel(
    int* __restrict__ bsums, int nb) {
  const int tid = threadIdx.x;
  const int lane = tid & 63, wid = tid >> 6;
  int v = (tid < nb) ? bsums[tid] : 0;
  int x = v;
  #pragma unroll
  for (int d = 1; d < 64; d <<= 1) {
    int y = __shfl_up(x, d, 64);
    if (lane >= d) x += y;
  }
  __shared__ int ws[4], wo[4];
  if (lane == 63) ws[wid] = x;
  __syncthreads();
  if (tid == 0) {
    int a = 0;
    #pragma unroll
    for (int w = 0; w < 4; ++w) { wo[w] = a; a += ws[w]; }
  }
  __syncthreads();
  if (tid < nb) bsums[tid] = x - v + wo[wid];
}

__global__ __launch_bounds__(256) void scan_add_kernel(
    int* __restrict__ row_start, int* __restrict__ cursor,
    const int* __restrict__ bsums, int n, int E) {
  const int i = blockIdx.x * 256 + threadIdx.x;
  if (i < n) {
    int r = row_start[i] + bsums[blockIdx.x];
    row_start[i] = r;
    cursor[i] = r;
  }
  if (i == 0) row_start[n] = E;
}

__global__ __launch_bounds__(256) void csr_scatter_kernel(
    const int* __restrict__ ei, const float* __restrict__ ea,
    int* __restrict__ cursor, uint4* __restrict__ rec, int E) {
  int e = blockIdx.x * 256 + threadIdx.x;
  if (e >= E) return;
  int s = ei[e];
  int d = ei[E + e];
  int p = atomicAdd(&cursor[d], 1);
  const float* eap = ea + (size_t)e * ED;
  uint4 r;
  r.x = (unsigned)s;
  r.y = h22u(mkh2(eap[0], eap[1]));
  r.z = h22u(mkh2(eap[2], eap[3]));
  r.w = h22u(mkh2(eap[4], 0.f));
  rec[p] = r;
}

// -------------------------------------------------------------------------
// GINE aggregation: wave/node, fused fp16 records, packed-fp16 math,
// fp32 accumulate.  z(bf16) = hbn[n] + sum relu(hbn[src] + ea@We + be)
// -------------------------------------------------------------------------
__device__ __forceinline__ void edge_accum(
    const uint4 rr, const uint2 hv, const h2 wA[5], const h2 wB[5],
    const h2 beA, const h2 beB, float& ax, float& ay, float& az, float& aw) {
  h2 m01 = u2h2(hv.x) + beA;
  h2 m23 = u2h2(hv.y) + beB;
  const h2 e01 = u2h2(rr.y), e23 = u2h2(rr.z), e44 = u2h2(rr.w);
  h2 t;
  t.x = e01.x; t.y = e01.x;  m01 += t * wA[0]; m23 += t * wB[0];
  t.x = e01.y; t.y = e01.y;  m01 += t * wA[1]; m23 += t * wB[1];
  t.x = e23.x; t.y = e23.x;  m01 += t * wA[2]; m23 += t * wB[2];
  t.x = e23.y; t.y = e23.y;  m01 += t * wA[3]; m23 += t * wB[3];
  t.x = e44.x; t.y = e44.x;  m01 += t * wA[4]; m23 += t * wB[4];
  const h2 z2 = {(_Float16)0.f, (_Float16)0.f};
  m01 = __builtin_elementwise_max(m01, z2);
  m23 = __builtin_elementwise_max(m23, z2);
  ax += (float)m01.x;
  ay += (float)m01.y;
  az += (float)m23.x;
  aw += (float)m23.y;
}

__global__ __launch_bounds__(256) void aggregate_kernel(
    const unsigned short* __restrict__ hbn, const uint4* __restrict__ rec,
    const float* __restrict__ We, const float* __restrict__ be,
    const int* __restrict__ row_start, unsigned short* __restrict__ z,
    int N) {
  const int lane = threadIdx.x & 63;
  int n = blockIdx.x * 4 + (threadIdx.x >> 6);
  if (n >= N) return;
  n = __builtin_amdgcn_readfirstlane(n);
  const int c = lane * 4;
  const h2 beA = mkh2(be[c], be[c + 1]);
  const h2 beB = mkh2(be[c + 2], be[c + 3]);
  h2 wA[5], wB[5];
  #pragma unroll
  for (int k = 0; k < 5; ++k) {
    wA[k] = mkh2(We[k * H + c], We[k * H + c + 1]);
    wB[k] = mkh2(We[k * H + c + 2], We[k * H + c + 3]);
  }
  float ax = 0.f, ay = 0.f, az = 0.f, aw = 0.f;
  const int s0 = __builtin_amdgcn_readfirstlane(row_start[n]);
  const int s1 = __builtin_amdgcn_readfirstlane(row_start[n + 1]);
  const uint4* rp = rec + s0;
  const int cnt = s1 - s0;
  int i = 0;
  for (; i + 4 <= cnt; i += 4) {
    const uint4 r0 = rp[i + 0];
    const uint4 r1 = rp[i + 1];
    const uint4 r2 = rp[i + 2];
    const uint4 r3 = rp[i + 3];
    const uint2 h0v = *(const uint2*)(hbn + (size_t)(int)r0.x * H + c);
    const uint2 h1v = *(const uint2*)(hbn + (size_t)(int)r1.x * H + c);
    const uint2 h2v = *(const uint2*)(hbn + (size_t)(int)r2.x * H + c);
    const uint2 h3v = *(const uint2*)(hbn + (size_t)(int)r3.x * H + c);
    edge_accum(r0, h0v, wA, wB, beA, beB, ax, ay, az, aw);
    edge_accum(r1, h1v, wA, wB, beA, beB, ax, ay, az, aw);
    edge_accum(r2, h2v, wA, wB, beA, beB, ax, ay, az, aw);
    edge_accum(r3, h3v, wA, wB, beA, beB, ax, ay, az, aw);
  }
  for (; i < cnt; ++i) {
    const uint4 r0 = rp[i];
    const uint2 h0v = *(const uint2*)(hbn + (size_t)(int)r0.x * H + c);
    edge_accum(r0, h0v, wA, wB, beA, beB, ax, ay, az, aw);
  }
  const uint2 hs = *(const uint2*)(hbn + (size_t)n * H + c);
  const h2 hsA = u2h2(hs.x), hsB = u2h2(hs.y);
  float zx = (float)hsA.x + ax;
  float zy = (float)hsA.y + ay;
  float zz = (float)hsB.x + az;
  float zw = (float)hsB.y + aw;
  uint2 o;
  o.x = (unsigned)f2bf(zx) | ((unsigned)f2bf(zy) << 16);
  o.y = (unsigned)f2bf(zz) | ((unsigned)f2bf(zw) << 16);
  *(uint2*)(z + (size_t)n * H + c) = o;
}

// -------------------------------------------------------------------------
extern "C" void kernel_launch(void* const* d_in, const int* in_sizes, int n_in,
                              void* d_out, int out_size, void* d_ws, size_t ws_size,
                              hipStream_t stream) {
  const float* x     = (const float*)d_in[0];
  const int*   ei    = (const int*)d_in[1];
  const float* ea    = (const float*)d_in[2];
  const int*   gid   = (const int*)d_in[3];
  const float* gemb  = (const float*)d_in[4];
  const float* W_in  = (const float*)d_in[5];
  const float* b_in  = (const float*)d_in[6];
  const float* gamma = (const float*)d_in[7];
  const float* beta  = (const float*)d_in[8];
  const float* We    = (const float*)d_in[9];
  const float* be    = (const float*)d_in[10];
  const float* W1    = (const float*)d_in[11];
  const float* b1    = (const float*)d_in[12];
  const float* W2    = (const float*)d_in[13];
  const float* b2    = (const float*)d_in[14];
  float* out = (float*)d_out;

  const int N = in_sizes[3];       // 59392
  const int E = in_sizes[1] / 2;   // 950272
  const int F = in_sizes[0] / N;   // 116
  const int NB = (N + 255) / 256;  // 232 scan blocks

  char* p = (char*)d_ws;
  auto take = [&](size_t bytes) {
    char* r = p;
    p += (bytes + 255) & ~(size_t)255;
    return r;
  };
  float* stats          = (float*)take(1024 * sizeof(float));
  int* deg              = (int*)take((size_t)N * 4);
  int* row_start        = (int*)take((size_t)(N + 1) * 4);
  int* cursor           = (int*)take((size_t)N * 4);
  int* bsums            = (int*)take((size_t)NB * 4);
  uint4* rec            = (uint4*)take((size_t)E * 16);
  unsigned short* Wtin  = (unsigned short*)take((size_t)H * KP * 2);
  unsigned short* Wt1   = (unsigned short*)take((size_t)H * H * 2);
  unsigned short* Wt2   = (unsigned short*)take((size_t)H * H * 2);
  unsigned short* Ac    = (unsigned short*)take((size_t)N * KP * 2);
  unsigned short* h0    = (unsigned short*)take((size_t)N * H * 2);
  unsigned short* hbn   = (unsigned short*)take((size_t)N * H * 2);
  unsigned short* z     = (unsigned short*)take((size_t)N * H * 2);
  unsigned short* hid   = (unsigned short*)take((size_t)N * H * 2);

  // zero BN accumulators + degree histogram (stats pad 4096B, then deg)
  (void)hipMemsetAsync(stats, 0, 4096 + (size_t)N * 4, stream);

  prep_weights_kernel<<<(H * KP + 2 * H * H) / 256, 256, 0, stream>>>(
      W_in, W1, W2, Wtin, Wt1, Wt2, F + EMB);

  // CSR build with fused records; multi-block scan
  csr_count_kernel<<<(E + 255) / 256, 256, 0, stream>>>(ei, deg, E);
  scan_blocks_kernel<<<NB, 256, 0, stream>>>(deg, row_start, bsums, N);
  scan_sums_kernel<<<1, 256, 0, stream>>>(bsums, NB);
  scan_add_kernel<<<NB, 256, 0, stream>>>(row_start, cursor, bsums, N, E);
  csr_scatter_kernel<<<(E + 255) / 256, 256, 0, stream>>>(ei, ea, cursor, rec, E);

  // input layer -> bf16 h0
  concat_kernel<<<((size_t)N * KP) / 256, 256, 0, stream>>>(x, gid, gemb, Ac, F, N);
  dim3 ggrid(H / 128, N / 128);
  gemm_mfma_kernel<1><<<ggrid, 256, 0, stream>>>(Ac, Wtin, b_in, h0, N, KP);

  // batchnorm -> fp16 hbn
  bn_stats_kernel<<<256, 256, 0, stream>>>(h0, stats, N);
  hbn_kernel<<<((size_t)N * H / 8) / 256, 256, 0, stream>>>(
      h0, stats, gamma, beta, hbn, 1.0f / (float)N);

  // GINE aggregate -> z (bf16)
  aggregate_kernel<<<(N + 3) / 4, 256, 0, stream>>>(hbn, rec, We, be,
                                                    row_start, z, N);

  // MLP
  gemm_mfma_kernel<1><<<ggrid, 256, 0, stream>>>(z, Wt1, b1, hid, N, H);
  gemm_mfma_kernel<0><<<ggrid, 256, 0, stream>>>(hid, Wt2, b2, out, N, H);

  (void)hipMemcpyAsync(out + (size_t)N * H, ea, (size_t)E * ED * sizeof(float),
                       hipMemcpyDeviceToDevice, stream);
}

// Round 6
// 415.491 us; speedup vs baseline: 2.0839x; 1.1563x over previous
//
#include <hip/hip_runtime.h>
#include <hip/hip_bf16.h>
#include <cstdint>
#include <cstddef>

#define H 256
#define EMB 16
#define ED 5
#define BN_EPS 1e-5f

typedef __attribute__((ext_vector_type(8))) short short8;
typedef __attribute__((ext_vector_type(4))) float f32x4;
typedef _Float16 h2 __attribute__((ext_vector_type(2)));

__device__ __forceinline__ unsigned short f2bf(float f) {
  unsigned int u = __float_as_uint(f);
  unsigned int r = (u + 0x7fffu + ((u >> 16) & 1u)) >> 16;
  return (unsigned short)r;
}
__device__ __forceinline__ unsigned int pk2bf(float a, float b) {
  return (unsigned int)f2bf(a) | ((unsigned int)f2bf(b) << 16);
}
__device__ __forceinline__ float bfhi(unsigned int u) {
  return __uint_as_float(u & 0xffff0000u);
}
__device__ __forceinline__ float bflo(unsigned int u) {
  return __uint_as_float(u << 16);
}
__device__ __forceinline__ h2 u2h2(unsigned int u) {
  union { unsigned int u; h2 h; } c;
  c.u = u;
  return c.h;
}
__device__ __forceinline__ unsigned int h22u(h2 h) {
  union { h2 h; unsigned int u; } c;
  c.h = h;
  return c.u;
}
__device__ __forceinline__ h2 mkh2(float a, float b) {
  h2 r;
  r.x = (_Float16)a;
  r.y = (_Float16)b;
  return r;
}

// -------------------------------------------------------------------------
// Prep: zero stats+deg; transpose W_in[:116]->Wtx[256][128]bf16,
// W1,W2 -> [256][256]bf16; T[g][c] = gemb[g]@W_in[116:132] + b_in (fp32).
// -------------------------------------------------------------------------
__global__ __launch_bounds__(256) void prep_kernel(
    const float* __restrict__ Win, const float* __restrict__ W1,
    const float* __restrict__ W2, const float* __restrict__ gemb,
    const float* __restrict__ b_in, unsigned short* __restrict__ Wtx,
    unsigned short* __restrict__ Wt1, unsigned short* __restrict__ Wt2,
    float* __restrict__ T, float* __restrict__ stats, int* __restrict__ deg,
    int N, int F, int G) {
  int idx = blockIdx.x * 256 + threadIdx.x;
  if (idx < 1024) stats[idx] = 0.f;
  if (idx < N) deg[idx] = 0;
  if (idx < 256 * 128) {
    int n = idx >> 7, k = idx & 127;
    Wtx[idx] = f2bf((k < F) ? Win[(size_t)k * H + n] : 0.f);
  } else if (idx < 256 * 128 + 65536) {
    int i2 = idx - 256 * 128;
    int n = i2 >> 8, k = i2 & 255;
    Wt1[i2] = f2bf(W1[(size_t)k * H + n]);
  } else if (idx < 256 * 128 + 131072) {
    int i2 = idx - 256 * 128 - 65536;
    int n = i2 >> 8, k = i2 & 255;
    Wt2[i2] = f2bf(W2[(size_t)k * H + n]);
  } else if (idx < 256 * 128 + 131072 + G * 256) {
    int i2 = idx - 256 * 128 - 131072;
    int g = i2 >> 8, c = i2 & 255;
    float s = b_in[c];
    #pragma unroll
    for (int k = 0; k < EMB; ++k)
      s = fmaf(gemb[g * EMB + k], Win[(size_t)(F + k) * H + c], s);
    T[i2] = s;
  }
}

// -------------------------------------------------------------------------
// Fused input GEMM: h0 = relu(x@Wx + T[gid]) , bf16 out, + BN column stats.
// x is fp32 [N,116]; staged to LDS as bf16. Wtx is [256][128] bf16 n-major.
// 128x128 tile, 4 waves. Epilogue accumulates per-column sum/sumsq -> stats.
// -------------------------------------------------------------------------
__global__ __launch_bounds__(256) void gemm_in_kernel(
    const float* __restrict__ x, const int* __restrict__ gid,
    const unsigned short* __restrict__ Wtx, const float* __restrict__ T,
    unsigned short* __restrict__ h0, float* __restrict__ stats, int F) {
  const int m0 = blockIdx.y * 128;
  const int n0 = blockIdx.x * 128;
  const int tid = threadIdx.x;
  const int lane = tid & 63;
  const int wave = tid >> 6;
  const int wm = (wave & 1) * 64;
  const int wn = (wave >> 1) * 64;
  const int l16 = lane & 15;
  const int quad = lane >> 4;
  __shared__ __align__(16) unsigned short As[128][40];
  __shared__ __align__(16) unsigned short Bs[128][40];
  __shared__ float cs[128], css[128];
  if (tid < 128) {
    cs[tid] = 0.f;
    css[tid] = 0.f;
  }
  f32x4 acc[4][4] = {};
  const int srow = tid >> 1;          // staging row 0..127
  const int half = tid & 1;           // which 16-col half of the 32-k window
  for (int k0 = 0; k0 < 128; k0 += 32) {
    __syncthreads();
    // A: x fp32 -> bf16
    {
      const float* xp = x + (size_t)(m0 + srow) * F;
      float4 xv[4];
      #pragma unroll
      for (int f = 0; f < 4; ++f) {
        int c = k0 + half * 16 + f * 4;
        xv[f] = (c < F) ? *(const float4*)(xp + c)
                        : make_float4(0.f, 0.f, 0.f, 0.f);
      }
      uint4 p0, p1;
      p0.x = pk2bf(xv[0].x, xv[0].y); p0.y = pk2bf(xv[0].z, xv[0].w);
      p0.z = pk2bf(xv[1].x, xv[1].y); p0.w = pk2bf(xv[1].z, xv[1].w);
      p1.x = pk2bf(xv[2].x, xv[2].y); p1.y = pk2bf(xv[2].z, xv[2].w);
      p1.z = pk2bf(xv[3].x, xv[3].y); p1.w = pk2bf(xv[3].z, xv[3].w);
      *(uint4*)(&As[srow][half * 16]) = p0;
      *(uint4*)(&As[srow][half * 16 + 8]) = p1;
    }
    // B: already bf16
    {
      const unsigned short* wp = Wtx + (size_t)(n0 + srow) * 128 + k0 + half * 16;
      *(uint4*)(&Bs[srow][half * 16]) = *(const uint4*)wp;
      *(uint4*)(&Bs[srow][half * 16 + 8]) = *(const uint4*)(wp + 8);
    }
    __syncthreads();
    short8 af[4], bf[4];
    #pragma unroll
    for (int i = 0; i < 4; ++i)
      af[i] = *(const short8*)(&As[wm + i * 16 + l16][quad * 8]);
    #pragma unroll
    for (int j = 0; j < 4; ++j)
      bf[j] = *(const short8*)(&Bs[wn + j * 16 + l16][quad * 8]);
    #pragma unroll
    for (int i = 0; i < 4; ++i)
      #pragma unroll
      for (int j = 0; j < 4; ++j)
        acc[i][j] = __builtin_amdgcn_mfma_f32_16x16x32_bf16(af[i], bf[j],
                                                            acc[i][j], 0, 0, 0);
  }
  int gi[4][4];
  #pragma unroll
  for (int i = 0; i < 4; ++i)
    #pragma unroll
    for (int r = 0; r < 4; ++r)
      gi[i][r] = gid[m0 + wm + i * 16 + quad * 4 + r];
  float ls[4] = {}, lss[4] = {};
  #pragma unroll
  for (int j = 0; j < 4; ++j) {
    const int col = n0 + wn + j * 16 + l16;
    #pragma unroll
    for (int i = 0; i < 4; ++i) {
      #pragma unroll
      for (int r = 0; r < 4; ++r) {
        const int row = m0 + wm + i * 16 + quad * 4 + r;
        float v = fmaxf(acc[i][j][r] + T[gi[i][r] * H + col], 0.f);
        h0[(size_t)row * H + col] = f2bf(v);
        ls[j] += v;
        lss[j] = fmaf(v, v, lss[j]);
      }
    }
  }
  #pragma unroll
  for (int j = 0; j < 4; ++j) {
    const int lc = wn + j * 16 + l16;
    atomicAdd(&cs[lc], ls[j]);
    atomicAdd(&css[lc], lss[j]);
  }
  __syncthreads();
  if (tid < 128) {
    atomicAdd(&stats[n0 + tid], cs[tid]);
    atomicAdd(&stats[H + n0 + tid], css[tid]);
  }
}

// -------------------------------------------------------------------------
// MFMA GEMM (K=256): C = relu(A@B + bias); Bt [256][256] bf16 n-major.
// -------------------------------------------------------------------------
template <int WRITE_BF16>
__global__ __launch_bounds__(256) void gemm_mfma_kernel(
    const unsigned short* __restrict__ A, const unsigned short* __restrict__ Bt,
    const float* __restrict__ bias, void* __restrict__ C, int N, int K) {
  const int m0 = blockIdx.y * 128;
  const int n0 = blockIdx.x * 128;
  const int tid = threadIdx.x;
  const int lane = tid & 63;
  const int wave = tid >> 6;
  const int wm = (wave & 1) * 64;
  const int wn = (wave >> 1) * 64;
  const int l16 = lane & 15;
  const int quad = lane >> 4;
  __shared__ __align__(16) unsigned short As[128][40];
  __shared__ __align__(16) unsigned short Bs[128][40];
  f32x4 acc[4][4] = {};
  const int r0s = tid >> 2, c0s = tid & 3;
  const int r1s = (tid + 256) >> 2;
  for (int k0 = 0; k0 < K; k0 += 32) {
    __syncthreads();
    *(float4*)(&As[r0s][c0s * 8]) =
        *(const float4*)(A + (size_t)(m0 + r0s) * K + k0 + c0s * 8);
    *(float4*)(&As[r1s][c0s * 8]) =
        *(const float4*)(A + (size_t)(m0 + r1s) * K + k0 + c0s * 8);
    *(float4*)(&Bs[r0s][c0s * 8]) =
        *(const float4*)(Bt + (size_t)(n0 + r0s) * K + k0 + c0s * 8);
    *(float4*)(&Bs[r1s][c0s * 8]) =
        *(const float4*)(Bt + (size_t)(n0 + r1s) * K + k0 + c0s * 8);
    __syncthreads();
    short8 af[4], bf[4];
    #pragma unroll
    for (int i = 0; i < 4; ++i)
      af[i] = *(const short8*)(&As[wm + i * 16 + l16][quad * 8]);
    #pragma unroll
    for (int j = 0; j < 4; ++j)
      bf[j] = *(const short8*)(&Bs[wn + j * 16 + l16][quad * 8]);
    #pragma unroll
    for (int i = 0; i < 4; ++i)
      #pragma unroll
      for (int j = 0; j < 4; ++j)
        acc[i][j] = __builtin_amdgcn_mfma_f32_16x16x32_bf16(af[i], bf[j],
                                                            acc[i][j], 0, 0, 0);
  }
  #pragma unroll
  for (int j = 0; j < 4; ++j) {
    const int col = n0 + wn + j * 16 + l16;
    const float bj = bias[col];
    #pragma unroll
    for (int i = 0; i < 4; ++i) {
      #pragma unroll
      for (int r = 0; r < 4; ++r) {
        const int row = m0 + wm + i * 16 + quad * 4 + r;
        float v = fmaxf(acc[i][j][r] + bj, 0.f);
        if (WRITE_BF16)
          ((unsigned short*)C)[(size_t)row * H + col] = f2bf(v);
        else
          ((float*)C)[(size_t)row * H + col] = v;
      }
    }
  }
}

// -------------------------------------------------------------------------
// hbn(fp16) = a*h0+b with BN finalize folded in
// -------------------------------------------------------------------------
__global__ __launch_bounds__(256) void hbn_kernel(
    const unsigned short* __restrict__ h0, const float* __restrict__ stats,
    const float* __restrict__ gamma, const float* __restrict__ beta,
    unsigned short* __restrict__ hbn, float inv_n) {
  __shared__ float sa[H], sb[H];
  {
    const int j = threadIdx.x;
    const float mu = stats[j] * inv_n;
    const float var = stats[H + j] * inv_n - mu * mu;
    const float rs = 1.0f / sqrtf(var + BN_EPS);
    const float a = gamma[j] * rs;
    sa[j] = a;
    sb[j] = beta[j] - mu * a;
  }
  __syncthreads();
  const size_t i = (size_t)blockIdx.x * 256 + threadIdx.x;
  const int c = ((int)(i & 31)) * 8;
  const uint4 hv = ((const uint4*)h0)[i];
  float r[8] = {bflo(hv.x), bfhi(hv.x), bflo(hv.y), bfhi(hv.y),
                bflo(hv.z), bfhi(hv.z), bflo(hv.w), bfhi(hv.w)};
  float o[8];
  #pragma unroll
  for (int t = 0; t < 8; ++t)
    o[t] = fmaf(sa[c + t], r[t], sb[c + t]);
  uint4 ov;
  ov.x = h22u(mkh2(o[0], o[1]));
  ov.y = h22u(mkh2(o[2], o[3]));
  ov.z = h22u(mkh2(o[4], o[5]));
  ov.w = h22u(mkh2(o[6], o[7]));
  ((uint4*)hbn)[i] = ov;
}

// -------------------------------------------------------------------------
// CSR build: count -> scan_blocks -> scan_finish -> scatter (+ea passthrough)
// -------------------------------------------------------------------------
__global__ __launch_bounds__(256) void csr_count_kernel(
    const int* __restrict__ ei, int* __restrict__ deg, int E) {
  int e = blockIdx.x * 256 + threadIdx.x;
  if (e < E) atomicAdd(&deg[ei[E + e]], 1);
}

__global__ __launch_bounds__(256) void scan_blocks_kernel(
    const int* __restrict__ deg, int* __restrict__ excl,
    int* __restrict__ bsums, int n) {
  const int tid = threadIdx.x;
  const int i = blockIdx.x * 256 + tid;
  const int lane = tid & 63, wid = tid >> 6;
  int v = (i < n) ? deg[i] : 0;
  int x = v;
  #pragma unroll
  for (int d = 1; d < 64; d <<= 1) {
    int y = __shfl_up(x, d, 64);
    if (lane >= d) x += y;
  }
  __shared__ int ws[4], wo[4];
  if (lane == 63) ws[wid] = x;
  __syncthreads();
  if (tid == 0) {
    int a = 0;
    #pragma unroll
    for (int w = 0; w < 4; ++w) { wo[w] = a; a += ws[w]; }
    bsums[blockIdx.x] = a;
  }
  __syncthreads();
  if (i < n) excl[i] = x - v + wo[wid];
}

// each block b adds prefix(bsums[0..b-1]) to its 256 entries
__global__ __launch_bounds__(256) void scan_finish_kernel(
    int* __restrict__ row_start, int* __restrict__ cursor,
    const int* __restrict__ bsums, int n, int E, int NB) {
  const int tid = threadIdx.x;
  const int b = blockIdx.x;
  int v = (tid < b && tid < NB) ? bsums[tid] : 0;
  int s = v;
  #pragma unroll
  for (int d = 32; d > 0; d >>= 1) s += __shfl_down(s, d, 64);
  __shared__ int ws[4];
  if ((tid & 63) == 0) ws[tid >> 6] = s;
  __syncthreads();
  const int S = ws[0] + ws[1] + ws[2] + ws[3];
  const int i = b * 256 + tid;
  if (i < n) {
    int r = row_start[i] + S;
    row_start[i] = r;
    cursor[i] = r;
  }
  if (b == 0 && tid == 0) row_start[n] = E;
}

__global__ __launch_bounds__(256) void csr_scatter_kernel(
    const int* __restrict__ ei, const float* __restrict__ ea,
    int* __restrict__ cursor, uint4* __restrict__ rec,
    float* __restrict__ ea_out, int E) {
  int e = blockIdx.x * 256 + threadIdx.x;
  if (e >= E) return;
  int s = ei[e];
  int d = ei[E + e];
  int p = atomicAdd(&cursor[d], 1);
  const float* eap = ea + (size_t)e * ED;
  const float e0 = eap[0], e1 = eap[1], e2 = eap[2], e3 = eap[3], e4 = eap[4];
  uint4 r;
  r.x = (unsigned)s;
  r.y = h22u(mkh2(e0, e1));
  r.z = h22u(mkh2(e2, e3));
  r.w = h22u(mkh2(e4, 0.f));
  rec[p] = r;
  // fused passthrough output (exact fp32)
  float* op = ea_out + (size_t)e * ED;
  op[0] = e0; op[1] = e1; op[2] = e2; op[3] = e3; op[4] = e4;
}

// -------------------------------------------------------------------------
// GINE aggregation: wave/node, fused fp16 records, packed-fp16 math,
// fp32 accumulate.  z(bf16) = hbn[n] + sum relu(hbn[src] + ea@We + be)
// -------------------------------------------------------------------------
__device__ __forceinline__ void edge_accum(
    const uint4 rr, const uint2 hv, const h2 wA[5], const h2 wB[5],
    const h2 beA, const h2 beB, float& ax, float& ay, float& az, float& aw) {
  h2 m01 = u2h2(hv.x) + beA;
  h2 m23 = u2h2(hv.y) + beB;
  const h2 e01 = u2h2(rr.y), e23 = u2h2(rr.z), e44 = u2h2(rr.w);
  h2 t;
  t.x = e01.x; t.y = e01.x;  m01 += t * wA[0]; m23 += t * wB[0];
  t.x = e01.y; t.y = e01.y;  m01 += t * wA[1]; m23 += t * wB[1];
  t.x = e23.x; t.y = e23.x;  m01 += t * wA[2]; m23 += t * wB[2];
  t.x = e23.y; t.y = e23.y;  m01 += t * wA[3]; m23 += t * wB[3];
  t.x = e44.x; t.y = e44.x;  m01 += t * wA[4]; m23 += t * wB[4];
  const h2 z2 = {(_Float16)0.f, (_Float16)0.f};
  m01 = __builtin_elementwise_max(m01, z2);
  m23 = __builtin_elementwise_max(m23, z2);
  ax += (float)m01.x;
  ay += (float)m01.y;
  az += (float)m23.x;
  aw += (float)m23.y;
}

__global__ __launch_bounds__(256) void aggregate_kernel(
    const unsigned short* __restrict__ hbn, const uint4* __restrict__ rec,
    const float* __restrict__ We, const float* __restrict__ be,
    const int* __restrict__ row_start, unsigned short* __restrict__ z,
    int N) {
  const int lane = threadIdx.x & 63;
  int n = blockIdx.x * 4 + (threadIdx.x >> 6);
  if (n >= N) return;
  n = __builtin_amdgcn_readfirstlane(n);
  const int c = lane * 4;
  const h2 beA = mkh2(be[c], be[c + 1]);
  const h2 beB = mkh2(be[c + 2], be[c + 3]);
  h2 wA[5], wB[5];
  #pragma unroll
  for (int k = 0; k < 5; ++k) {
    wA[k] = mkh2(We[k * H + c], We[k * H + c + 1]);
    wB[k] = mkh2(We[k * H + c + 2], We[k * H + c + 3]);
  }
  float ax = 0.f, ay = 0.f, az = 0.f, aw = 0.f;
  const int s0 = __builtin_amdgcn_readfirstlane(row_start[n]);
  const int s1 = __builtin_amdgcn_readfirstlane(row_start[n + 1]);
  const uint4* rp = rec + s0;
  const int cnt = s1 - s0;
  int i = 0;
  for (; i + 4 <= cnt; i += 4) {
    const uint4 r0 = rp[i + 0];
    const uint4 r1 = rp[i + 1];
    const uint4 r2 = rp[i + 2];
    const uint4 r3 = rp[i + 3];
    const uint2 h0v = *(const uint2*)(hbn + (size_t)(int)r0.x * H + c);
    const uint2 h1v = *(const uint2*)(hbn + (size_t)(int)r1.x * H + c);
    const uint2 h2v = *(const uint2*)(hbn + (size_t)(int)r2.x * H + c);
    const uint2 h3v = *(const uint2*)(hbn + (size_t)(int)r3.x * H + c);
    edge_accum(r0, h0v, wA, wB, beA, beB, ax, ay, az, aw);
    edge_accum(r1, h1v, wA, wB, beA, beB, ax, ay, az, aw);
    edge_accum(r2, h2v, wA, wB, beA, beB, ax, ay, az, aw);
    edge_accum(r3, h3v, wA, wB, beA, beB, ax, ay, az, aw);
  }
  for (; i < cnt; ++i) {
    const uint4 r0 = rp[i];
    const uint2 h0v = *(const uint2*)(hbn + (size_t)(int)r0.x * H + c);
    edge_accum(r0, h0v, wA, wB, beA, beB, ax, ay, az, aw);
  }
  const uint2 hs = *(const uint2*)(hbn + (size_t)n * H + c);
  const h2 hsA = u2h2(hs.x), hsB = u2h2(hs.y);
  float zx = (float)hsA.x + ax;
  float zy = (float)hsA.y + ay;
  float zz = (float)hsB.x + az;
  float zw = (float)hsB.y + aw;
  uint2 o;
  o.x = pk2bf(zx, zy);
  o.y = pk2bf(zz, zw);
  *(uint2*)(z + (size_t)n * H + c) = o;
}

// -------------------------------------------------------------------------
extern "C" void kernel_launch(void* const* d_in, const int* in_sizes, int n_in,
                              void* d_out, int out_size, void* d_ws, size_t ws_size,
                              hipStream_t stream) {
  const float* x     = (const float*)d_in[0];
  const int*   ei    = (const int*)d_in[1];
  const float* ea    = (const float*)d_in[2];
  const int*   gid   = (const int*)d_in[3];
  const float* gemb  = (const float*)d_in[4];
  const float* W_in  = (const float*)d_in[5];
  const float* b_in  = (const float*)d_in[6];
  const float* gamma = (const float*)d_in[7];
  const float* beta  = (const float*)d_in[8];
  const float* We    = (const float*)d_in[9];
  const float* be    = (const float*)d_in[10];
  const float* W1    = (const float*)d_in[11];
  const float* b1    = (const float*)d_in[12];
  const float* W2    = (const float*)d_in[13];
  const float* b2    = (const float*)d_in[14];
  float* out = (float*)d_out;

  const int N = in_sizes[3];           // 59392
  const int E = in_sizes[1] / 2;       // 950272
  const int F = in_sizes[0] / N;       // 116
  const int G = in_sizes[4] / EMB;     // 8
  const int NB = (N + 255) / 256;      // 232

  char* p = (char*)d_ws;
  auto take = [&](size_t bytes) {
    char* r = p;
    p += (bytes + 255) & ~(size_t)255;
    return r;
  };
  float* stats          = (float*)take(1024 * sizeof(float));
  int* deg              = (int*)take((size_t)N * 4);
  int* row_start        = (int*)take((size_t)(N + 1) * 4);
  int* cursor           = (int*)take((size_t)N * 4);
  int* bsums            = (int*)take((size_t)NB * 4);
  uint4* rec            = (uint4*)take((size_t)E * 16);
  unsigned short* Wtx   = (unsigned short*)take((size_t)256 * 128 * 2);
  unsigned short* Wt1   = (unsigned short*)take((size_t)H * H * 2);
  unsigned short* Wt2   = (unsigned short*)take((size_t)H * H * 2);
  float* T              = (float*)take((size_t)G * H * 4);
  unsigned short* h0    = (unsigned short*)take((size_t)N * H * 2);
  unsigned short* hbn   = (unsigned short*)take((size_t)N * H * 2);
  unsigned short* z     = (unsigned short*)take((size_t)N * H * 2);
  unsigned short* hid   = (unsigned short*)take((size_t)N * H * 2);

  // 1) prep: zeros + weight transposes + T table
  {
    int total = 256 * 128 + 131072 + G * 256;
    int nb = (total + 255) / 256;
    if (nb < (N + 255) / 256) nb = (N + 255) / 256;
    prep_kernel<<<nb, 256, 0, stream>>>(W_in, W1, W2, gemb, b_in, Wtx, Wt1,
                                        Wt2, T, stats, deg, N, F, G);
  }

  // 2-5) CSR build with fused records + ea passthrough
  csr_count_kernel<<<(E + 255) / 256, 256, 0, stream>>>(ei, deg, E);
  scan_blocks_kernel<<<NB, 256, 0, stream>>>(deg, row_start, bsums, N);
  scan_finish_kernel<<<NB, 256, 0, stream>>>(row_start, cursor, bsums, N, E, NB);
  csr_scatter_kernel<<<(E + 255) / 256, 256, 0, stream>>>(
      ei, ea, cursor, rec, out + (size_t)N * H, E);

  // 6) fused input layer (concat-free, BN stats in epilogue)
  dim3 ggrid(H / 128, N / 128);
  gemm_in_kernel<<<ggrid, 256, 0, stream>>>(x, gid, Wtx, T, h0, stats, F);

  // 7) BN finalize + normalize -> fp16 hbn
  hbn_kernel<<<((size_t)N * H / 8) / 256, 256, 0, stream>>>(
      h0, stats, gamma, beta, hbn, 1.0f / (float)N);

  // 8) GINE aggregate -> z (bf16)
  aggregate_kernel<<<(N + 3) / 4, 256, 0, stream>>>(hbn, rec, We, be,
                                                    row_start, z, N);

  // 9-10) MLP
  gemm_mfma_kernel<1><<<ggrid, 256, 0, stream>>>(z, Wt1, b1, hid, N, H);
  gemm_mfma_kernel<0><<<ggrid, 256, 0, stream>>>(hid, Wt2, b2, out, N, H);
}

// Round 7
// 390.999 us; speedup vs baseline: 2.2145x; 1.0626x over previous
//
#include <hip/hip_runtime.h>
#include <hip/hip_bf16.h>
#include <cstdint>
#include <cstddef>

#define H 256
#define EMB 16
#define ED 5
#define BN_EPS 1e-5f

typedef __attribute__((ext_vector_type(8))) short short8;
typedef __attribute__((ext_vector_type(4))) float f32x4;
typedef _Float16 h2 __attribute__((ext_vector_type(2)));

__device__ __forceinline__ unsigned short f2bf(float f) {
  unsigned int u = __float_as_uint(f);
  unsigned int r = (u + 0x7fffu + ((u >> 16) & 1u)) >> 16;
  return (unsigned short)r;
}
__device__ __forceinline__ unsigned int pk2bf(float a, float b) {
  return (unsigned int)f2bf(a) | ((unsigned int)f2bf(b) << 16);
}
__device__ __forceinline__ float bfhi(unsigned int u) {
  return __uint_as_float(u & 0xffff0000u);
}
__device__ __forceinline__ float bflo(unsigned int u) {
  return __uint_as_float(u << 16);
}
__device__ __forceinline__ h2 u2h2(unsigned int u) {
  union { unsigned int u; h2 h; } c;
  c.u = u;
  return c.h;
}
__device__ __forceinline__ unsigned int h22u(h2 h) {
  union { h2 h; unsigned int u; } c;
  c.h = h;
  return c.u;
}
__device__ __forceinline__ h2 mkh2(float a, float b) {
  h2 r;
  r.x = (_Float16)a;
  r.y = (_Float16)b;
  return r;
}

// -------------------------------------------------------------------------
// Prep: zero stats+deg; transpose W_in[:116]->Wtx[256][128]bf16,
// W1,W2 -> [256][256]bf16; T[g][c] = gemb[g]@W_in[116:132] + b_in (fp32).
// -------------------------------------------------------------------------
__global__ __launch_bounds__(256) void prep_kernel(
    const float* __restrict__ Win, const float* __restrict__ W1,
    const float* __restrict__ W2, const float* __restrict__ gemb,
    const float* __restrict__ b_in, unsigned short* __restrict__ Wtx,
    unsigned short* __restrict__ Wt1, unsigned short* __restrict__ Wt2,
    float* __restrict__ T, float* __restrict__ stats, int* __restrict__ deg,
    int N, int F, int G) {
  int idx = blockIdx.x * 256 + threadIdx.x;
  if (idx < 1024) stats[idx] = 0.f;
  if (idx < N) deg[idx] = 0;
  if (idx < 256 * 128) {
    int n = idx >> 7, k = idx & 127;
    Wtx[idx] = f2bf((k < F) ? Win[(size_t)k * H + n] : 0.f);
  } else if (idx < 256 * 128 + 65536) {
    int i2 = idx - 256 * 128;
    int n = i2 >> 8, k = i2 & 255;
    Wt1[i2] = f2bf(W1[(size_t)k * H + n]);
  } else if (idx < 256 * 128 + 131072) {
    int i2 = idx - 256 * 128 - 65536;
    int n = i2 >> 8, k = i2 & 255;
    Wt2[i2] = f2bf(W2[(size_t)k * H + n]);
  } else if (idx < 256 * 128 + 131072 + G * 256) {
    int i2 = idx - 256 * 128 - 131072;
    int g = i2 >> 8, c = i2 & 255;
    float s = b_in[c];
    #pragma unroll
    for (int k = 0; k < EMB; ++k)
      s = fmaf(gemb[g * EMB + k], Win[(size_t)(F + k) * H + c], s);
    T[i2] = s;
  }
}

// -------------------------------------------------------------------------
// Fused input GEMM: h0 = relu(x@Wx + T[gid]) bf16, + BN column stats.
// -------------------------------------------------------------------------
__global__ __launch_bounds__(256) void gemm_in_kernel(
    const float* __restrict__ x, const int* __restrict__ gid,
    const unsigned short* __restrict__ Wtx, const float* __restrict__ T,
    unsigned short* __restrict__ h0, float* __restrict__ stats, int F) {
  const int m0 = blockIdx.y * 128;
  const int n0 = blockIdx.x * 128;
  const int tid = threadIdx.x;
  const int lane = tid & 63;
  const int wave = tid >> 6;
  const int wm = (wave & 1) * 64;
  const int wn = (wave >> 1) * 64;
  const int l16 = lane & 15;
  const int quad = lane >> 4;
  __shared__ __align__(16) unsigned short As[128][40];
  __shared__ __align__(16) unsigned short Bs[128][40];
  __shared__ float cs[128], css[128];
  if (tid < 128) {
    cs[tid] = 0.f;
    css[tid] = 0.f;
  }
  f32x4 acc[4][4] = {};
  const int srow = tid >> 1;
  const int half = tid & 1;
  for (int k0 = 0; k0 < 128; k0 += 32) {
    __syncthreads();
    {
      const float* xp = x + (size_t)(m0 + srow) * F;
      float4 xv[4];
      #pragma unroll
      for (int f = 0; f < 4; ++f) {
        int c = k0 + half * 16 + f * 4;
        xv[f] = (c < F) ? *(const float4*)(xp + c)
                        : make_float4(0.f, 0.f, 0.f, 0.f);
      }
      uint4 p0, p1;
      p0.x = pk2bf(xv[0].x, xv[0].y); p0.y = pk2bf(xv[0].z, xv[0].w);
      p0.z = pk2bf(xv[1].x, xv[1].y); p0.w = pk2bf(xv[1].z, xv[1].w);
      p1.x = pk2bf(xv[2].x, xv[2].y); p1.y = pk2bf(xv[2].z, xv[2].w);
      p1.z = pk2bf(xv[3].x, xv[3].y); p1.w = pk2bf(xv[3].z, xv[3].w);
      *(uint4*)(&As[srow][half * 16]) = p0;
      *(uint4*)(&As[srow][half * 16 + 8]) = p1;
    }
    {
      const unsigned short* wp = Wtx + (size_t)(n0 + srow) * 128 + k0 + half * 16;
      *(uint4*)(&Bs[srow][half * 16]) = *(const uint4*)wp;
      *(uint4*)(&Bs[srow][half * 16 + 8]) = *(const uint4*)(wp + 8);
    }
    __syncthreads();
    short8 af[4], bf[4];
    #pragma unroll
    for (int i = 0; i < 4; ++i)
      af[i] = *(const short8*)(&As[wm + i * 16 + l16][quad * 8]);
    #pragma unroll
    for (int j = 0; j < 4; ++j)
      bf[j] = *(const short8*)(&Bs[wn + j * 16 + l16][quad * 8]);
    #pragma unroll
    for (int i = 0; i < 4; ++i)
      #pragma unroll
      for (int j = 0; j < 4; ++j)
        acc[i][j] = __builtin_amdgcn_mfma_f32_16x16x32_bf16(af[i], bf[j],
                                                            acc[i][j], 0, 0, 0);
  }
  int gi[4][4];
  #pragma unroll
  for (int i = 0; i < 4; ++i)
    #pragma unroll
    for (int r = 0; r < 4; ++r)
      gi[i][r] = gid[m0 + wm + i * 16 + quad * 4 + r];
  float ls[4] = {}, lss[4] = {};
  #pragma unroll
  for (int j = 0; j < 4; ++j) {
    const int col = n0 + wn + j * 16 + l16;
    #pragma unroll
    for (int i = 0; i < 4; ++i) {
      #pragma unroll
      for (int r = 0; r < 4; ++r) {
        const int row = m0 + wm + i * 16 + quad * 4 + r;
        float v = fmaxf(acc[i][j][r] + T[gi[i][r] * H + col], 0.f);
        h0[(size_t)row * H + col] = f2bf(v);
        ls[j] += v;
        lss[j] = fmaf(v, v, lss[j]);
      }
    }
  }
  #pragma unroll
  for (int j = 0; j < 4; ++j) {
    const int lc = wn + j * 16 + l16;
    atomicAdd(&cs[lc], ls[j]);
    atomicAdd(&css[lc], lss[j]);
  }
  __syncthreads();
  if (tid < 128) {
    atomicAdd(&stats[n0 + tid], cs[tid]);
    atomicAdd(&stats[H + n0 + tid], css[tid]);
  }
}

// -------------------------------------------------------------------------
// Fused MLP: out = relu( relu(z@W1+b1) @ W2 + b2 ), hid tile in LDS.
// Block = 64 rows x 256 cols, 4 waves (each 64x64).
// -------------------------------------------------------------------------
__global__ __launch_bounds__(256) void mlp_kernel(
    const unsigned short* __restrict__ z, const unsigned short* __restrict__ Wt1,
    const unsigned short* __restrict__ Wt2, const float* __restrict__ b1,
    const float* __restrict__ b2, float* __restrict__ out) {
  const int m0 = blockIdx.x * 64;
  const int tid = threadIdx.x;
  const int lane = tid & 63;
  const int wave = tid >> 6;   // n-block 0..3
  const int wn = wave * 64;
  const int l16 = lane & 15;
  const int quad = lane >> 4;
  __shared__ __align__(16) unsigned short As[64][40];
  __shared__ __align__(16) unsigned short Bs[256][40];
  __shared__ __align__(16) unsigned short hidS[64][264];
  f32x4 acc[4][4] = {};
  const int ar = tid >> 2, ac = tid & 3;
  // ---- layer 1 ----
  for (int k0 = 0; k0 < 256; k0 += 32) {
    __syncthreads();
    *(float4*)(&As[ar][ac * 8]) =
        *(const float4*)(z + (size_t)(m0 + ar) * H + k0 + ac * 8);
    #pragma unroll
    for (int t = 0; t < 4; ++t) {
      int r = ar + t * 64;
      *(float4*)(&Bs[r][ac * 8]) =
          *(const float4*)(Wt1 + (size_t)r * H + k0 + ac * 8);
    }
    __syncthreads();
    short8 af[4], bf[4];
    #pragma unroll
    for (int i = 0; i < 4; ++i)
      af[i] = *(const short8*)(&As[i * 16 + l16][quad * 8]);
    #pragma unroll
    for (int j = 0; j < 4; ++j)
      bf[j] = *(const short8*)(&Bs[wn + j * 16 + l16][quad * 8]);
    #pragma unroll
    for (int i = 0; i < 4; ++i)
      #pragma unroll
      for (int j = 0; j < 4; ++j)
        acc[i][j] = __builtin_amdgcn_mfma_f32_16x16x32_bf16(af[i], bf[j],
                                                            acc[i][j], 0, 0, 0);
  }
  #pragma unroll
  for (int j = 0; j < 4; ++j) {
    const int col = wn + j * 16 + l16;
    const float bj = b1[col];
    #pragma unroll
    for (int i = 0; i < 4; ++i)
      #pragma unroll
      for (int r = 0; r < 4; ++r) {
        const int row = i * 16 + quad * 4 + r;
        hidS[row][col] = f2bf(fmaxf(acc[i][j][r] + bj, 0.f));
      }
  }
  #pragma unroll
  for (int i = 0; i < 4; ++i)
    #pragma unroll
    for (int j = 0; j < 4; ++j)
      acc[i][j] = (f32x4){0.f, 0.f, 0.f, 0.f};
  // ---- layer 2 (A = hidS in LDS) ----
  for (int k0 = 0; k0 < 256; k0 += 32) {
    __syncthreads();
    #pragma unroll
    for (int t = 0; t < 4; ++t) {
      int r = ar + t * 64;
      *(float4*)(&Bs[r][ac * 8]) =
          *(const float4*)(Wt2 + (size_t)r * H + k0 + ac * 8);
    }
    __syncthreads();
    short8 af[4], bf[4];
    #pragma unroll
    for (int i = 0; i < 4; ++i)
      af[i] = *(const short8*)(&hidS[i * 16 + l16][k0 + quad * 8]);
    #pragma unroll
    for (int j = 0; j < 4; ++j)
      bf[j] = *(const short8*)(&Bs[wn + j * 16 + l16][quad * 8]);
    #pragma unroll
    for (int i = 0; i < 4; ++i)
      #pragma unroll
      for (int j = 0; j < 4; ++j)
        acc[i][j] = __builtin_amdgcn_mfma_f32_16x16x32_bf16(af[i], bf[j],
                                                            acc[i][j], 0, 0, 0);
  }
  #pragma unroll
  for (int j = 0; j < 4; ++j) {
    const int col = wn + j * 16 + l16;
    const float bj = b2[col];
    #pragma unroll
    for (int i = 0; i < 4; ++i)
      #pragma unroll
      for (int r = 0; r < 4; ++r) {
        const int row = m0 + i * 16 + quad * 4 + r;
        out[(size_t)row * H + col] = fmaxf(acc[i][j][r] + bj, 0.f);
      }
  }
}

// -------------------------------------------------------------------------
// hbn(fp16) = a*h0 + b + be  (BN finalize + GINE edge-bias folded in)
// -------------------------------------------------------------------------
__global__ __launch_bounds__(256) void hbn_kernel(
    const unsigned short* __restrict__ h0, const float* __restrict__ stats,
    const float* __restrict__ gamma, const float* __restrict__ beta,
    const float* __restrict__ be, unsigned short* __restrict__ hbn,
    float inv_n) {
  __shared__ float sa[H], sb[H];
  {
    const int j = threadIdx.x;
    const float mu = stats[j] * inv_n;
    const float var = stats[H + j] * inv_n - mu * mu;
    const float rs = 1.0f / sqrtf(var + BN_EPS);
    const float a = gamma[j] * rs;
    sa[j] = a;
    sb[j] = beta[j] - mu * a + be[j];
  }
  __syncthreads();
  const size_t i = (size_t)blockIdx.x * 256 + threadIdx.x;
  const int c = ((int)(i & 31)) * 8;
  const uint4 hv = ((const uint4*)h0)[i];
  float r[8] = {bflo(hv.x), bfhi(hv.x), bflo(hv.y), bfhi(hv.y),
                bflo(hv.z), bfhi(hv.z), bflo(hv.w), bfhi(hv.w)};
  float o[8];
  #pragma unroll
  for (int t = 0; t < 8; ++t)
    o[t] = fmaf(sa[c + t], r[t], sb[c + t]);
  uint4 ov;
  ov.x = h22u(mkh2(o[0], o[1]));
  ov.y = h22u(mkh2(o[2], o[3]));
  ov.z = h22u(mkh2(o[4], o[5]));
  ov.w = h22u(mkh2(o[6], o[7]));
  ((uint4*)hbn)[i] = ov;
}

// -------------------------------------------------------------------------
// CSR build
// -------------------------------------------------------------------------
__global__ __launch_bounds__(256) void csr_count_kernel(
    const int* __restrict__ ei, int* __restrict__ deg, int E) {
  int e = blockIdx.x * 256 + threadIdx.x;
  if (e < E) atomicAdd(&deg[ei[E + e]], 1);
}

__global__ __launch_bounds__(256) void scan_blocks_kernel(
    const int* __restrict__ deg, int* __restrict__ excl,
    int* __restrict__ bsums, int n) {
  const int tid = threadIdx.x;
  const int i = blockIdx.x * 256 + tid;
  const int lane = tid & 63, wid = tid >> 6;
  int v = (i < n) ? deg[i] : 0;
  int x = v;
  #pragma unroll
  for (int d = 1; d < 64; d <<= 1) {
    int y = __shfl_up(x, d, 64);
    if (lane >= d) x += y;
  }
  __shared__ int ws[4], wo[4];
  if (lane == 63) ws[wid] = x;
  __syncthreads();
  if (tid == 0) {
    int a = 0;
    #pragma unroll
    for (int w = 0; w < 4; ++w) { wo[w] = a; a += ws[w]; }
    bsums[blockIdx.x] = a;
  }
  __syncthreads();
  if (i < n) excl[i] = x - v + wo[wid];
}

__global__ __launch_bounds__(256) void scan_finish_kernel(
    int* __restrict__ row_start, int* __restrict__ cursor,
    const int* __restrict__ bsums, int n, int E, int NB) {
  const int tid = threadIdx.x;
  const int b = blockIdx.x;
  int v = (tid < b && tid < NB) ? bsums[tid] : 0;
  int s = v;
  #pragma unroll
  for (int d = 32; d > 0; d >>= 1) s += __shfl_down(s, d, 64);
  __shared__ int ws[4];
  if ((tid & 63) == 0) ws[tid >> 6] = s;
  __syncthreads();
  const int S = ws[0] + ws[1] + ws[2] + ws[3];
  const int i = b * 256 + tid;
  if (i < n) {
    int r = row_start[i] + S;
    row_start[i] = r;
    cursor[i] = r;
  }
  if (b == 0 && tid == 0) row_start[n] = E;
}

__global__ __launch_bounds__(256) void csr_scatter_kernel(
    const int* __restrict__ ei, const float* __restrict__ ea,
    int* __restrict__ cursor, uint4* __restrict__ rec,
    float* __restrict__ ea_out, int E) {
  int e = blockIdx.x * 256 + threadIdx.x;
  if (e >= E) return;
  int s = ei[e];
  int d = ei[E + e];
  int p = atomicAdd(&cursor[d], 1);
  const float* eap = ea + (size_t)e * ED;
  const float e0 = eap[0], e1 = eap[1], e2 = eap[2], e3 = eap[3], e4 = eap[4];
  uint4 r;
  r.x = (unsigned)s;
  r.y = h22u(mkh2(e0, e1));
  r.z = h22u(mkh2(e2, e3));
  r.w = h22u(mkh2(e4, 0.f));
  rec[p] = r;
  float* op = ea_out + (size_t)e * ED;
  op[0] = e0; op[1] = e1; op[2] = e2; op[3] = e3; op[4] = e4;
}

// -------------------------------------------------------------------------
// GINE aggregation: wave/node, unroll 8. be pre-folded into hbn.
// z(bf16) = (hbn[n]-be) + sum relu(hbn[src] + ea@We)
// -------------------------------------------------------------------------
__device__ __forceinline__ void edge_accum(
    const uint4 rr, const uint2 hv, const h2 wA[5], const h2 wB[5],
    float& ax, float& ay, float& az, float& aw) {
  h2 m01 = u2h2(hv.x);
  h2 m23 = u2h2(hv.y);
  const h2 e01 = u2h2(rr.y), e23 = u2h2(rr.z), e44 = u2h2(rr.w);
  h2 t;
  t.x = e01.x; t.y = e01.x;  m01 += t * wA[0]; m23 += t * wB[0];
  t.x = e01.y; t.y = e01.y;  m01 += t * wA[1]; m23 += t * wB[1];
  t.x = e23.x; t.y = e23.x;  m01 += t * wA[2]; m23 += t * wB[2];
  t.x = e23.y; t.y = e23.y;  m01 += t * wA[3]; m23 += t * wB[3];
  t.x = e44.x; t.y = e44.x;  m01 += t * wA[4]; m23 += t * wB[4];
  const h2 z2 = {(_Float16)0.f, (_Float16)0.f};
  m01 = __builtin_elementwise_max(m01, z2);
  m23 = __builtin_elementwise_max(m23, z2);
  ax += (float)m01.x;
  ay += (float)m01.y;
  az += (float)m23.x;
  aw += (float)m23.y;
}

__global__ __launch_bounds__(256) void aggregate_kernel(
    const unsigned short* __restrict__ hbn, const uint4* __restrict__ rec,
    const float* __restrict__ We, const float* __restrict__ be,
    const int* __restrict__ row_start, unsigned short* __restrict__ z,
    int N) {
  const int lane = threadIdx.x & 63;
  int n = blockIdx.x * 4 + (threadIdx.x >> 6);
  if (n >= N) return;
  n = __builtin_amdgcn_readfirstlane(n);
  const int c = lane * 4;
  const float4 be4 = *(const float4*)(be + c);
  h2 wA[5], wB[5];
  #pragma unroll
  for (int k = 0; k < 5; ++k) {
    wA[k] = mkh2(We[k * H + c], We[k * H + c + 1]);
    wB[k] = mkh2(We[k * H + c + 2], We[k * H + c + 3]);
  }
  float ax = 0.f, ay = 0.f, az = 0.f, aw = 0.f;
  const int s0 = __builtin_amdgcn_readfirstlane(row_start[n]);
  const int s1 = __builtin_amdgcn_readfirstlane(row_start[n + 1]);
  const uint4* rp = rec + s0;
  const int cnt = s1 - s0;
  int i = 0;
  for (; i + 8 <= cnt; i += 8) {
    uint4 rr[8];
    uint2 hh[8];
    #pragma unroll
    for (int u = 0; u < 8; ++u) rr[u] = rp[i + u];
    #pragma unroll
    for (int u = 0; u < 8; ++u)
      hh[u] = *(const uint2*)(hbn + (size_t)(int)rr[u].x * H + c);
    #pragma unroll
    for (int u = 0; u < 8; ++u)
      edge_accum(rr[u], hh[u], wA, wB, ax, ay, az, aw);
  }
  for (; i + 4 <= cnt; i += 4) {
    uint4 rr[4];
    uint2 hh[4];
    #pragma unroll
    for (int u = 0; u < 4; ++u) rr[u] = rp[i + u];
    #pragma unroll
    for (int u = 0; u < 4; ++u)
      hh[u] = *(const uint2*)(hbn + (size_t)(int)rr[u].x * H + c);
    #pragma unroll
    for (int u = 0; u < 4; ++u)
      edge_accum(rr[u], hh[u], wA, wB, ax, ay, az, aw);
  }
  for (; i < cnt; ++i) {
    const uint4 r0 = rp[i];
    const uint2 h0v = *(const uint2*)(hbn + (size_t)(int)r0.x * H + c);
    edge_accum(r0, h0v, wA, wB, ax, ay, az, aw);
  }
  const uint2 hs = *(const uint2*)(hbn + (size_t)n * H + c);
  const h2 hsA = u2h2(hs.x), hsB = u2h2(hs.y);
  float zx = (float)hsA.x - be4.x + ax;
  float zy = (float)hsA.y - be4.y + ay;
  float zz = (float)hsB.x - be4.z + az;
  float zw = (float)hsB.y - be4.w + aw;
  uint2 o;
  o.x = pk2bf(zx, zy);
  o.y = pk2bf(zz, zw);
  *(uint2*)(z + (size_t)n * H + c) = o;
}

// -------------------------------------------------------------------------
extern "C" void kernel_launch(void* const* d_in, const int* in_sizes, int n_in,
                              void* d_out, int out_size, void* d_ws, size_t ws_size,
                              hipStream_t stream) {
  const float* x     = (const float*)d_in[0];
  const int*   ei    = (const int*)d_in[1];
  const float* ea    = (const float*)d_in[2];
  const int*   gid   = (const int*)d_in[3];
  const float* gemb  = (const float*)d_in[4];
  const float* W_in  = (const float*)d_in[5];
  const float* b_in  = (const float*)d_in[6];
  const float* gamma = (const float*)d_in[7];
  const float* beta  = (const float*)d_in[8];
  const float* We    = (const float*)d_in[9];
  const float* be    = (const float*)d_in[10];
  const float* W1    = (const float*)d_in[11];
  const float* b1    = (const float*)d_in[12];
  const float* W2    = (const float*)d_in[13];
  const float* b2    = (const float*)d_in[14];
  float* out = (float*)d_out;

  const int N = in_sizes[3];           // 59392
  const int E = in_sizes[1] / 2;       // 950272
  const int F = in_sizes[0] / N;       // 116
  const int G = in_sizes[4] / EMB;     // 8
  const int NB = (N + 255) / 256;      // 232

  char* p = (char*)d_ws;
  auto take = [&](size_t bytes) {
    char* r = p;
    p += (bytes + 255) & ~(size_t)255;
    return r;
  };
  float* stats          = (float*)take(1024 * sizeof(float));
  int* deg              = (int*)take((size_t)N * 4);
  int* row_start        = (int*)take((size_t)(N + 1) * 4);
  int* cursor           = (int*)take((size_t)N * 4);
  int* bsums            = (int*)take((size_t)NB * 4);
  uint4* rec            = (uint4*)take((size_t)E * 16);
  unsigned short* Wtx   = (unsigned short*)take((size_t)256 * 128 * 2);
  unsigned short* Wt1   = (unsigned short*)take((size_t)H * H * 2);
  unsigned short* Wt2   = (unsigned short*)take((size_t)H * H * 2);
  float* T              = (float*)take((size_t)G * H * 4);
  unsigned short* h0    = (unsigned short*)take((size_t)N * H * 2);
  unsigned short* hbn   = (unsigned short*)take((size_t)N * H * 2);
  unsigned short* z     = (unsigned short*)take((size_t)N * H * 2);

  // 1) prep
  {
    int total = 256 * 128 + 131072 + G * 256;
    int nb = (total + 255) / 256;
    if (nb < (N + 255) / 256) nb = (N + 255) / 256;
    prep_kernel<<<nb, 256, 0, stream>>>(W_in, W1, W2, gemb, b_in, Wtx, Wt1,
                                        Wt2, T, stats, deg, N, F, G);
  }

  // 2-5) CSR build + ea passthrough
  csr_count_kernel<<<(E + 255) / 256, 256, 0, stream>>>(ei, deg, E);
  scan_blocks_kernel<<<NB, 256, 0, stream>>>(deg, row_start, bsums, N);
  scan_finish_kernel<<<NB, 256, 0, stream>>>(row_start, cursor, bsums, N, E, NB);
  csr_scatter_kernel<<<(E + 255) / 256, 256, 0, stream>>>(
      ei, ea, cursor, rec, out + (size_t)N * H, E);

  // 6) input layer + BN stats
  dim3 ggrid(H / 128, N / 128);
  gemm_in_kernel<<<ggrid, 256, 0, stream>>>(x, gid, Wtx, T, h0, stats, F);

  // 7) BN finalize + be fold -> fp16 hbn
  hbn_kernel<<<((size_t)N * H / 8) / 256, 256, 0, stream>>>(
      h0, stats, gamma, beta, be, hbn, 1.0f / (float)N);

  // 8) GINE aggregate -> z (bf16)
  aggregate_kernel<<<(N + 3) / 4, 256, 0, stream>>>(hbn, rec, We, be,
                                                    row_start, z, N);

  // 9) fused MLP -> out
  mlp_kernel<<<N / 64, 256, 0, stream>>>(z, Wt1, Wt2, b1, b2, out);
}